// Round 1
// baseline (7469.126 us; speedup 1.0000x reference)
//
#include <hip/hip_runtime.h>

// ---------------- model constants ----------------
#define NLAYER 4
#define DMODEL 2048
#define NHEAD  16
#define HEADD  128
#define FFDIM  8192
#define RLORA  16
#define SEQLEN 1024
#define NBATCH 2
#define NTOK   (NBATCH*SEQLEN)   // 2048

typedef __bf16 bf16x8 __attribute__((ext_vector_type(8)));
typedef float  f32x4  __attribute__((ext_vector_type(4)));
typedef unsigned short us8 __attribute__((ext_vector_type(8)));

__device__ __forceinline__ unsigned short f2b(float f) {
  unsigned int u = __builtin_bit_cast(unsigned int, f);
  u += 0x7FFFu + ((u >> 16) & 1u);          // round-to-nearest-even
  return (unsigned short)(u >> 16);
}
__device__ __forceinline__ float b2f(unsigned short s) {
  unsigned int u = ((unsigned int)s) << 16;
  return __builtin_bit_cast(float, u);
}

// ---------------- embedding gather ----------------
__global__ void k_embed(const int* __restrict__ ids, const float* __restrict__ emb,
                        float* __restrict__ x) {
  int row = blockIdx.x;                       // token index 0..2047
  int id = ids[row];
  const float4* src = (const float4*)(emb + (size_t)id * DMODEL);
  float4* dst = (float4*)(x + (size_t)row * DMODEL);
  for (int i = threadIdx.x; i < DMODEL / 4; i += 256) dst[i] = src[i];
}

// ---------------- RMSNorm -> bf16 ----------------
__global__ void k_rmsnorm(const float* __restrict__ x, const float* __restrict__ w,
                          unsigned short* __restrict__ h) {
  int row = blockIdx.x, t = threadIdx.x;
  const float* xr = x + (size_t)row * DMODEL;
  float4 a = ((const float4*)xr)[t];
  float4 b = ((const float4*)xr)[t + 256];
  float ss = a.x*a.x + a.y*a.y + a.z*a.z + a.w*a.w
           + b.x*b.x + b.y*b.y + b.z*b.z + b.w*b.w;
  for (int m = 32; m; m >>= 1) ss += __shfl_xor(ss, m);
  __shared__ float red[4];
  if ((t & 63) == 0) red[t >> 6] = ss;
  __syncthreads();
  ss = red[0] + red[1] + red[2] + red[3];
  float rs = rsqrtf(ss * (1.0f / DMODEL) + 1e-5f);
  float4 wa = ((const float4*)w)[t];
  float4 wb = ((const float4*)w)[t + 256];
  ushort4 oa, ob;
  oa.x = f2b(a.x * wa.x * rs); oa.y = f2b(a.y * wa.y * rs);
  oa.z = f2b(a.z * wa.z * rs); oa.w = f2b(a.w * wa.w * rs);
  ob.x = f2b(b.x * wb.x * rs); ob.y = f2b(b.y * wb.y * rs);
  ob.z = f2b(b.z * wb.z * rs); ob.w = f2b(b.w * wb.w * rs);
  ushort4* hr = (ushort4*)(h + (size_t)row * DMODEL);
  hr[t] = oa;
  hr[t + 256] = ob;
}

// ---------------- NT GEMM: C[m,n] = sum_k A[m,k]*B[n,k] ----------------
// A: bf16 (ushort) [M,K]; B: f32 [N,K] converted to bf16 in staging.
// MODE 0: Cf = acc; 1: Cf = acc + Res; 2: Cb = bf16(acc); 3: Cb = bf16(silu(Gaux)*acc)
template<int MODE>
__global__ __launch_bounds__(256, 2)
void k_gemm(const unsigned short* __restrict__ A, const float* __restrict__ B,
            float* __restrict__ Cf, unsigned short* __restrict__ Cb,
            const float* __restrict__ Res, const unsigned short* __restrict__ Gaux,
            int N, int K) {
  __shared__ unsigned char lds[128 * 32 * 2 * 2];     // As (8KB) + Bs (8KB)
  unsigned char* As = lds;
  unsigned char* Bs = lds + 128 * 32 * 2;
  const int t = threadIdx.x;
  const int l = t & 63, w = t >> 6;
  const int wr = w >> 1, wc = w & 1;
  const int m0 = blockIdx.y << 7, n0 = blockIdx.x << 7;
  // staging: thread -> (row, k-half)
  const int sr = t >> 1, skh = (t & 1) << 4;
  const int sByte = sr * 64 + (skh << 1);
  const int sSwz = (sr & 3) << 4;
  const unsigned short* Ap = A + (size_t)(m0 + sr) * K + skh;
  const float* Bp = B + (size_t)(n0 + sr) * K + skh;
  // fragment read: 16B slot (l>>4) XOR row-swizzle ((row&3)==(l&3))
  const int kOff = (((l >> 4) << 4)) ^ ((l & 3) << 4);
  const int arow = wr * 64 + (l & 15);
  const int brow = wc * 64 + (l & 15);
  f32x4 acc[4][4];
  #pragma unroll
  for (int mi = 0; mi < 4; mi++)
    #pragma unroll
    for (int ni = 0; ni < 4; ni++) { f32x4 z = {0.f, 0.f, 0.f, 0.f}; acc[mi][ni] = z; }

  for (int kt = 0; kt < K; kt += 32) {
    // A: 16 bf16 -> two 16B chunks
    uint4 a0 = *(const uint4*)(Ap + kt);
    uint4 a1 = *(const uint4*)(Ap + kt + 8);
    // B: 16 f32 -> cvt -> 16 bf16
    float4 f0 = *(const float4*)(Bp + kt);
    float4 f1 = *(const float4*)(Bp + kt + 4);
    float4 f2 = *(const float4*)(Bp + kt + 8);
    float4 f3 = *(const float4*)(Bp + kt + 12);
    us8 q0, q1;
    q0[0]=f2b(f0.x); q0[1]=f2b(f0.y); q0[2]=f2b(f0.z); q0[3]=f2b(f0.w);
    q0[4]=f2b(f1.x); q0[5]=f2b(f1.y); q0[6]=f2b(f1.z); q0[7]=f2b(f1.w);
    q1[0]=f2b(f2.x); q1[1]=f2b(f2.y); q1[2]=f2b(f2.z); q1[3]=f2b(f2.w);
    q1[4]=f2b(f3.x); q1[5]=f2b(f3.y); q1[6]=f2b(f3.z); q1[7]=f2b(f3.w);
    *(uint4*)(As + ((sByte)      ^ sSwz)) = a0;
    *(uint4*)(As + ((sByte + 16) ^ sSwz)) = a1;
    *(us8*) (Bs + ((sByte)      ^ sSwz)) = q0;
    *(us8*) (Bs + ((sByte + 16) ^ sSwz)) = q1;
    __syncthreads();
    bf16x8 af[4], bfr[4];
    #pragma unroll
    for (int i = 0; i < 4; i++) {
      af[i]  = *(const bf16x8*)(As + (arow + 16 * i) * 64 + kOff);
      bfr[i] = *(const bf16x8*)(Bs + (brow + 16 * i) * 64 + kOff);
    }
    #pragma unroll
    for (int mi = 0; mi < 4; mi++)
      #pragma unroll
      for (int ni = 0; ni < 4; ni++)
        acc[mi][ni] = __builtin_amdgcn_mfma_f32_16x16x32_bf16(af[mi], bfr[ni], acc[mi][ni], 0, 0, 0);
    __syncthreads();
  }
  // epilogue: C/D layout col=lane&15, row=(lane>>4)*4+reg  [HW-verified]
  const int rbase = (l >> 4) << 2;
  const int cl = l & 15;
  #pragma unroll
  for (int mi = 0; mi < 4; mi++) {
    #pragma unroll
    for (int ni = 0; ni < 4; ni++) {
      #pragma unroll
      for (int rr = 0; rr < 4; rr++) {
        int row = m0 + wr * 64 + mi * 16 + rbase + rr;
        int col = n0 + wc * 64 + ni * 16 + cl;
        size_t idx = (size_t)row * N + col;
        float val = acc[mi][ni][rr];
        if constexpr (MODE == 0) Cf[idx] = val;
        if constexpr (MODE == 1) Cf[idx] = val + Res[idx];
        if constexpr (MODE == 2) Cb[idx] = f2b(val);
        if constexpr (MODE == 3) {
          float gv = b2f(Gaux[idx]);
          val *= gv / (1.0f + __expf(-gv));
          Cb[idx] = f2b(val);
        }
      }
    }
  }
}

// ---------------- LoRA ----------------
__global__ void k_lora_down(const unsigned short* __restrict__ h, const float* __restrict__ Am,
                            float* __restrict__ tb) {
  int t = threadIdx.x;
  int m = blockIdx.x * 16 + (t >> 4), r = t & 15;
  const unsigned short* hr = h + (size_t)m * DMODEL;
  const float* ar = Am + (size_t)r * DMODEL;
  float acc = 0.f;
  for (int d = 0; d < DMODEL; d += 4) {
    ushort4 hv = *(const ushort4*)(hr + d);
    float4 av = *(const float4*)(ar + d);
    acc += b2f(hv.x)*av.x + b2f(hv.y)*av.y + b2f(hv.z)*av.z + b2f(hv.w)*av.w;
  }
  tb[(size_t)m * RLORA + r] = acc;
}

__global__ void k_lora_up(const float* __restrict__ tb, const float* __restrict__ Bm,
                          float* __restrict__ out) {
  int tid = blockIdx.x * 256 + threadIdx.x;    // m*DMODEL + e
  int m = tid >> 11, e = tid & (DMODEL - 1);
  const float* tr = tb + (size_t)m * RLORA;
  const float* br = Bm + (size_t)e * RLORA;
  float acc = 0.f;
  #pragma unroll
  for (int r = 0; r < RLORA; r += 4) {
    float4 tv = *(const float4*)(tr + r);
    float4 bv = *(const float4*)(br + r);
    acc += tv.x*bv.x + tv.y*bv.y + tv.z*bv.z + tv.w*bv.w;
  }
  out[tid] += 2.0f * acc;                      // ALPHA_OVER_R = 32/16
}

// ---------------- RoPE ----------------
__global__ void k_rope_table(float* __restrict__ ct, float* __restrict__ st) {
  int tid = blockIdx.x * 256 + threadIdx.x;    // SEQLEN*64
  int s = tid >> 6, i = tid & 63;
  float inv = __expf(-((float)i / 64.0f) * logf(10000.0f));
  float ang = (float)s * inv;
  ct[tid] = cosf(ang);
  st[tid] = sinf(ang);
}

__global__ void k_rope(float* __restrict__ q, float* __restrict__ k,
                       const float* __restrict__ ct, const float* __restrict__ st) {
  int tid = blockIdx.x * 256 + threadIdx.x;    // B*S*H*64
  int i = tid & 63;
  int hh = (tid >> 6) & (NHEAD - 1);
  int s = (tid >> 10) & (SEQLEN - 1);
  int b = tid >> 20;
  size_t base = (((size_t)(b * SEQLEN + s)) * NHEAD + hh) * HEADD;
  float c = ct[s * 64 + i], sn = st[s * 64 + i];
  float q0 = q[base + i], q1 = q[base + i + 64];
  q[base + i]      = q0 * c - q1 * sn;
  q[base + i + 64] = q1 * c + q0 * sn;
  float k0 = k[base + i], k1 = k[base + i + 64];
  k[base + i]      = k0 * c - k1 * sn;
  k[base + i + 64] = k1 * c + k0 * sn;
}

// ---------------- fused causal attention (fp32 flash) ----------------
__global__ __launch_bounds__(256)
void k_attn(const float* __restrict__ q, const float* __restrict__ k,
            const float* __restrict__ v, const int* __restrict__ am,
            unsigned short* __restrict__ o) {
  __shared__ float Qs[32][132];
  __shared__ float Ks[32][132];
  __shared__ float Vs[32][132];
  __shared__ float Ps[32][36];
  int qt = blockIdx.x, hh = blockIdx.y, b = blockIdx.z;
  int t = threadIdx.x, l = t & 63, w = t >> 6;
  int rl = w * 8 + (l >> 3);                  // local q row 0..31
  int qg = qt * 32 + rl;
  int cbase = l & 7;
  // load Q tile
  for (int ii = 0; ii < 4; ii++) {
    int fi = t + 256 * ii; int row = fi >> 5; int c4 = (fi & 31) << 2;
    *(float4*)&Qs[row][c4] =
      *(const float4*)(q + ((((size_t)b * SEQLEN + qt * 32 + row) * NHEAD + hh) << 7) + c4);
  }
  float4 oa[4];
  #pragma unroll
  for (int jj = 0; jj < 4; jj++) oa[jj] = make_float4(0.f, 0.f, 0.f, 0.f);
  float m_run = -3e38f, l_run = 0.f;
  for (int kb = 0; kb <= qt; kb++) {
    __syncthreads();                           // protect prior Vs reads / order Qs
    for (int ii = 0; ii < 4; ii++) {
      int fi = t + 256 * ii; int row = fi >> 5; int c4 = (fi & 31) << 2;
      size_t gb = ((((size_t)b * SEQLEN + kb * 32 + row) * NHEAD + hh) << 7) + c4;
      *(float4*)&Ks[row][c4] = *(const float4*)(k + gb);
      *(float4*)&Vs[row][c4] = *(const float4*)(v + gb);
    }
    __syncthreads();
    float sv[4] = {0.f, 0.f, 0.f, 0.f};
    for (int d4 = 0; d4 < HEADD; d4 += 4) {
      float4 qv = *(const float4*)&Qs[rl][d4];
      #pragma unroll
      for (int j = 0; j < 4; j++) {
        float4 kv = *(const float4*)&Ks[cbase + 8 * j][d4];
        sv[j] += qv.x*kv.x + qv.y*kv.y + qv.z*kv.z + qv.w*kv.w;
      }
    }
    float mt = -3e38f;
    #pragma unroll
    for (int j = 0; j < 4; j++) {
      int kg = kb * 32 + cbase + 8 * j;
      float pad = (1.0f - (float)am[b * SEQLEN + kg]) * (-1e9f);
      sv[j] = sv[j] * 0.08838834764831845f + ((kg <= qg) ? 0.0f : -1e9f) + pad;
      mt = fmaxf(mt, sv[j]);
    }
    mt = fmaxf(mt, __shfl_xor(mt, 1));
    mt = fmaxf(mt, __shfl_xor(mt, 2));
    mt = fmaxf(mt, __shfl_xor(mt, 4));
    float mnew = fmaxf(m_run, mt);
    float corr = __expf(m_run - mnew);
    float psum = 0.f;
    #pragma unroll
    for (int j = 0; j < 4; j++) {
      sv[j] = __expf(sv[j] - mnew);
      psum += sv[j];
      Ps[rl][cbase + 8 * j] = sv[j];
    }
    psum += __shfl_xor(psum, 1);
    psum += __shfl_xor(psum, 2);
    psum += __shfl_xor(psum, 4);
    l_run = l_run * corr + psum;
    m_run = mnew;
    #pragma unroll
    for (int jj = 0; jj < 4; jj++) {
      oa[jj].x *= corr; oa[jj].y *= corr; oa[jj].z *= corr; oa[jj].w *= corr;
    }
    for (int kk = 0; kk < 32; kk++) {
      float p = Ps[rl][kk];
      #pragma unroll
      for (int jj = 0; jj < 4; jj++) {
        float4 vv = *(const float4*)&Vs[kk][cbase * 4 + 32 * jj];
        oa[jj].x += p * vv.x; oa[jj].y += p * vv.y;
        oa[jj].z += p * vv.z; oa[jj].w += p * vv.w;
      }
    }
  }
  float inv_l = 1.0f / l_run;
  size_t ob = (((size_t)b * SEQLEN + qg) * NHEAD + hh) << 7;
  #pragma unroll
  for (int jj = 0; jj < 4; jj++) {
    int d = cbase * 4 + 32 * jj;
    ushort4 ov;
    ov.x = f2b(oa[jj].x * inv_l); ov.y = f2b(oa[jj].y * inv_l);
    ov.z = f2b(oa[jj].z * inv_l); ov.w = f2b(oa[jj].w * inv_l);
    *(ushort4*)(o + ob + d) = ov;
  }
}

// ---------------- pooling + final RMS ----------------
__global__ void k_pool(const float* __restrict__ x, const int* __restrict__ am,
                       const float* __restrict__ fn, float* __restrict__ pooled) {
  int b = blockIdx.x, t = threadIdx.x;
  __shared__ float red[4];
  float fc = 0.f;
  for (int i = t; i < SEQLEN; i += 256) fc += (float)am[b * SEQLEN + i];
  for (int m = 32; m; m >>= 1) fc += __shfl_xor(fc, m);
  if ((t & 63) == 0) red[t >> 6] = fc;
  __syncthreads();
  int idx = (int)(red[0] + red[1] + red[2] + red[3]) - 1;
  const float* xr = x + ((size_t)b * SEQLEN + idx) * DMODEL;
  float4 a = ((const float4*)xr)[t], c = ((const float4*)xr)[t + 256];
  float ss = a.x*a.x + a.y*a.y + a.z*a.z + a.w*a.w
           + c.x*c.x + c.y*c.y + c.z*c.z + c.w*c.w;
  for (int m = 32; m; m >>= 1) ss += __shfl_xor(ss, m);
  __syncthreads();
  if ((t & 63) == 0) red[t >> 6] = ss;
  __syncthreads();
  ss = red[0] + red[1] + red[2] + red[3];
  float rs = rsqrtf(ss * (1.0f / DMODEL) + 1e-5f);
  float4 w0 = ((const float4*)fn)[t], w1 = ((const float4*)fn)[t + 256];
  float4 o0, o1;
  o0.x = a.x*rs*w0.x; o0.y = a.y*rs*w0.y; o0.z = a.z*rs*w0.z; o0.w = a.w*rs*w0.w;
  o1.x = c.x*rs*w1.x; o1.y = c.y*rs*w1.y; o1.z = c.z*rs*w1.z; o1.w = c.w*rs*w1.w;
  ((float4*)(pooled + (size_t)b * DMODEL))[t] = o0;
  ((float4*)(pooled + (size_t)b * DMODEL))[t + 256] = o1;
}

// ---------------- classification head ----------------
__global__ void k_head1(const float* __restrict__ pooled, const float* __restrict__ W1,
                        const float* __restrict__ b1, float* __restrict__ h1) {
  int bi = blockIdx.x;
  int b = bi >> 3, e = ((bi & 7) << 8) + threadIdx.x;
  const float* pr = pooled + (size_t)b * DMODEL;
  const float* wr = W1 + (size_t)e * DMODEL;
  float acc = 0.f;
  for (int d = 0; d < DMODEL; d += 4) {
    float4 pv = *(const float4*)(pr + d);
    float4 wv = *(const float4*)(wr + d);
    acc += pv.x*wv.x + pv.y*wv.y + pv.z*wv.z + pv.w*wv.w;
  }
  h1[(size_t)b * DMODEL + e] = tanhf(acc + b1[e]);
}

__global__ void k_head2(const float* __restrict__ h1, const float* __restrict__ W2,
                        const float* __restrict__ b2, float* __restrict__ out) {
  int bi = blockIdx.x;           // 6 = b*3+c
  int b = bi / 3, c = bi % 3;
  int l = threadIdx.x;
  float acc = 0.f;
  for (int e = l; e < DMODEL; e += 64)
    acc += h1[(size_t)b * DMODEL + e] * W2[(size_t)c * DMODEL + e];
  for (int m = 32; m; m >>= 1) acc += __shfl_xor(acc, m);
  if (l == 0) out[b * 3 + c] = acc + b2[c];
}

__global__ void k_sentinel(float* out) {
  if (threadIdx.x < 6) out[threadIdx.x] = -12345.0f;
}

// ---------------- launch ----------------
extern "C" void kernel_launch(void* const* d_in, const int* in_sizes, int n_in,
                              void* d_out, int out_size, void* d_ws, size_t ws_size,
                              hipStream_t stream) {
  const int*   ids = (const int*)d_in[0];
  const int*   am  = (const int*)d_in[1];
  const float* emb = (const float*)d_in[2];
  const float* Wq  = (const float*)d_in[3];
  const float* Wk  = (const float*)d_in[4];
  const float* Wv  = (const float*)d_in[5];
  const float* Wo  = (const float*)d_in[6];
  const float* Aq  = (const float*)d_in[7];
  const float* Bq  = (const float*)d_in[8];
  const float* Av  = (const float*)d_in[9];
  const float* Bv  = (const float*)d_in[10];
  const float* Wg  = (const float*)d_in[11];
  const float* Wu  = (const float*)d_in[12];
  const float* Wd  = (const float*)d_in[13];
  const float* n1  = (const float*)d_in[14];
  const float* n2  = (const float*)d_in[15];
  const float* fn  = (const float*)d_in[16];
  const float* hW1 = (const float*)d_in[17];
  const float* hb1 = (const float*)d_in[18];
  const float* hW2 = (const float*)d_in[19];
  const float* hb2 = (const float*)d_in[20];
  float* out = (float*)d_out;

  // workspace layout (~93 MB): x | h | region{q,k,v,o / g,act} | tails
  const size_t XOFF = 0;
  const size_t HOFF = 16777216;
  const size_t ROFF = 25165824;
  const size_t RSZ  = 67108864;
  const size_t TOFF = ROFF + RSZ;                  // 92274688
  const size_t NEED = TOFF + 131072 + 262144 + 262144 + 16384 + 16384;
  if (ws_size < NEED) {                            // diagnosable clean failure
    k_sentinel<<<1, 64, 0, stream>>>(out);
    return;
  }
  char* ws = (char*)d_ws;
  float*          x   = (float*)(ws + XOFF);
  unsigned short* h   = (unsigned short*)(ws + HOFF);
  float*          q   = (float*)(ws + ROFF);
  float*          k   = (float*)(ws + ROFF + 16777216);
  float*          v   = (float*)(ws + ROFF + 33554432);
  unsigned short* o   = (unsigned short*)(ws + ROFF + 50331648);
  unsigned short* g   = (unsigned short*)(ws + ROFF);            // reuse after attn
  unsigned short* act = (unsigned short*)(ws + ROFF + 33554432); // reuse after attn
  float* tb     = (float*)(ws + TOFF);
  float* ct     = (float*)(ws + TOFF + 131072);
  float* st     = (float*)(ws + TOFF + 131072 + 262144);
  float* pooled = (float*)(ws + TOFF + 131072 + 524288);
  float* h1     = (float*)(ws + TOFF + 131072 + 524288 + 16384);

  k_embed<<<NTOK, 256, 0, stream>>>(ids, emb, x);
  k_rope_table<<<SEQLEN * 64 / 256, 256, 0, stream>>>(ct, st);

  dim3 g16(16, 16), g64(64, 16), ga(32, NHEAD, NBATCH);
  for (int lay = 0; lay < NLAYER; lay++) {
    k_rmsnorm<<<NTOK, 256, 0, stream>>>(x, n1 + (size_t)lay * DMODEL, h);
    k_gemm<0><<<g16, 256, 0, stream>>>(h, Wq + (size_t)lay * DMODEL * DMODEL, q, nullptr, nullptr, nullptr, DMODEL, DMODEL);
    k_gemm<0><<<g16, 256, 0, stream>>>(h, Wk + (size_t)lay * DMODEL * DMODEL, k, nullptr, nullptr, nullptr, DMODEL, DMODEL);
    k_gemm<0><<<g16, 256, 0, stream>>>(h, Wv + (size_t)lay * DMODEL * DMODEL, v, nullptr, nullptr, nullptr, DMODEL, DMODEL);
    k_lora_down<<<NTOK / 16, 256, 0, stream>>>(h, Aq + (size_t)lay * RLORA * DMODEL, tb);
    k_lora_up<<<NTOK * DMODEL / 256, 256, 0, stream>>>(tb, Bq + (size_t)lay * DMODEL * RLORA, q);
    k_lora_down<<<NTOK / 16, 256, 0, stream>>>(h, Av + (size_t)lay * RLORA * DMODEL, tb);
    k_lora_up<<<NTOK * DMODEL / 256, 256, 0, stream>>>(tb, Bv + (size_t)lay * DMODEL * RLORA, v);
    k_rope<<<NBATCH * SEQLEN * NHEAD * 64 / 256, 256, 0, stream>>>(q, k, ct, st);
    k_attn<<<ga, 256, 0, stream>>>(q, k, v, am, o);
    k_gemm<1><<<g16, 256, 0, stream>>>(o, Wo + (size_t)lay * DMODEL * DMODEL, x, nullptr, x, nullptr, DMODEL, DMODEL);
    k_rmsnorm<<<NTOK, 256, 0, stream>>>(x, n2 + (size_t)lay * DMODEL, h);
    k_gemm<2><<<g64, 256, 0, stream>>>(h, Wg + (size_t)lay * FFDIM * DMODEL, nullptr, g, nullptr, nullptr, FFDIM, DMODEL);
    k_gemm<3><<<g64, 256, 0, stream>>>(h, Wu + (size_t)lay * FFDIM * DMODEL, nullptr, act, nullptr, g, FFDIM, DMODEL);
    k_gemm<1><<<g16, 256, 0, stream>>>(act, Wd + (size_t)lay * DMODEL * FFDIM, x, nullptr, x, nullptr, DMODEL, FFDIM);
  }
  k_pool<<<NBATCH, 256, 0, stream>>>(x, am, fn, pooled);
  k_head1<<<16, 256, 0, stream>>>(pooled, hW1, hb1, h1);
  k_head2<<<6, 64, 0, stream>>>(h1, hW2, hb2, out);
}

// Round 2
// 4312.036 us; speedup vs baseline: 1.7322x; 1.7322x over previous
//
#include <hip/hip_runtime.h>

// ---------------- model constants ----------------
#define NLAYER 4
#define DMODEL 2048
#define NHEAD  16
#define HEADD  128
#define FFDIM  8192
#define RLORA  16
#define SEQLEN 1024
#define NBATCH 2
#define NTOK   (NBATCH*SEQLEN)   // 2048

typedef __bf16 bf16x8 __attribute__((ext_vector_type(8)));
typedef float  f32x4  __attribute__((ext_vector_type(4)));
typedef unsigned short us8 __attribute__((ext_vector_type(8)));

__device__ __forceinline__ unsigned short f2b(float f) {
  unsigned int u = __builtin_bit_cast(unsigned int, f);
  u += 0x7FFFu + ((u >> 16) & 1u);          // round-to-nearest-even
  return (unsigned short)(u >> 16);
}
__device__ __forceinline__ float b2f(unsigned short s) {
  unsigned int u = ((unsigned int)s) << 16;
  return __builtin_bit_cast(float, u);
}
// V-LDS swizzle: reads (d=base+lane) 2-way free; writes (d=4*lane+j) 4-way
__device__ __forceinline__ int vswz(int d) {
  return (((d >> 2) & 7) ^ ((d & 3) << 1)) << 4;
}

// ---------------- embedding gather ----------------
__global__ void k_embed(const int* __restrict__ ids, const float* __restrict__ emb,
                        float* __restrict__ x) {
  int row = blockIdx.x;
  int id = ids[row];
  const float4* src = (const float4*)(emb + (size_t)id * DMODEL);
  float4* dst = (float4*)(x + (size_t)row * DMODEL);
  for (int i = threadIdx.x; i < DMODEL / 4; i += 256) dst[i] = src[i];
}

// ---------------- weight fp32 -> bf16 ----------------
__global__ void k_cvt16(const float* __restrict__ s, unsigned short* __restrict__ d, int n8) {
  int stride = gridDim.x * 256;
  for (int i = blockIdx.x * 256 + threadIdx.x; i < n8; i += stride) {
    size_t si = (size_t)i * 2;
    float4 a = ((const float4*)s)[si];
    float4 b = ((const float4*)s)[si + 1];
    us8 o;
    o[0]=f2b(a.x); o[1]=f2b(a.y); o[2]=f2b(a.z); o[3]=f2b(a.w);
    o[4]=f2b(b.x); o[5]=f2b(b.y); o[6]=f2b(b.z); o[7]=f2b(b.w);
    ((us8*)d)[i] = o;
  }
}

// ---------------- RMSNorm -> bf16 ----------------
__global__ void k_rmsnorm(const float* __restrict__ x, const float* __restrict__ w,
                          unsigned short* __restrict__ h) {
  int row = blockIdx.x, t = threadIdx.x;
  const float* xr = x + (size_t)row * DMODEL;
  float4 a = ((const float4*)xr)[t];
  float4 b = ((const float4*)xr)[t + 256];
  float ss = a.x*a.x + a.y*a.y + a.z*a.z + a.w*a.w
           + b.x*b.x + b.y*b.y + b.z*b.z + b.w*b.w;
  for (int m = 32; m; m >>= 1) ss += __shfl_xor(ss, m);
  __shared__ float red[4];
  if ((t & 63) == 0) red[t >> 6] = ss;
  __syncthreads();
  ss = red[0] + red[1] + red[2] + red[3];
  float rs = rsqrtf(ss * (1.0f / DMODEL) + 1e-5f);
  float4 wa = ((const float4*)w)[t];
  float4 wb = ((const float4*)w)[t + 256];
  ushort4 oa, ob;
  oa.x = f2b(a.x * wa.x * rs); oa.y = f2b(a.y * wa.y * rs);
  oa.z = f2b(a.z * wa.z * rs); oa.w = f2b(a.w * wa.w * rs);
  ob.x = f2b(b.x * wb.x * rs); ob.y = f2b(b.y * wb.y * rs);
  ob.z = f2b(b.z * wb.z * rs); ob.w = f2b(b.w * wb.w * rs);
  ushort4* hr = (ushort4*)(h + (size_t)row * DMODEL);
  hr[t] = oa;
  hr[t + 256] = ob;
}

// ---------------- NT GEMM: C[m,n] = sum_k A[m,k]*B[n,k] ----------------
// A: bf16 [M,K]; B: BW? bf16 : f32 (converted in staging).
// MODE 0: Cf=acc; 1: Cf=acc+Res; 2: Cb=bf16(acc); 3: Cb=bf16(silu(Gaux)*acc)
template<int MODE, int BW>
__global__ __launch_bounds__(256, 2)
void k_gemm(const unsigned short* __restrict__ A, const void* __restrict__ Bv,
            float* __restrict__ Cf, unsigned short* __restrict__ Cb,
            const float* __restrict__ Res, const unsigned short* __restrict__ Gaux,
            int N, int K) {
  __shared__ unsigned char lds[128 * 32 * 2 * 2];
  unsigned char* As = lds;
  unsigned char* Bs = lds + 128 * 32 * 2;
  const int t = threadIdx.x;
  const int l = t & 63, w = t >> 6;
  const int wr = w >> 1, wc = w & 1;
  const int m0 = blockIdx.y << 7, n0 = blockIdx.x << 7;
  const int sr = t >> 1, skh = (t & 1) << 4;
  const int sByte = sr * 64 + (skh << 1);
  const int sSwz = (sr & 3) << 4;
  const unsigned short* Ap = A + (size_t)(m0 + sr) * K + skh;
  const float* Bp32 = (const float*)Bv + (size_t)(n0 + sr) * K + skh;
  const unsigned short* Bp16 = (const unsigned short*)Bv + (size_t)(n0 + sr) * K + skh;
  const int kOff = (((l >> 4) << 4)) ^ ((l & 3) << 4);
  const int arow = wr * 64 + (l & 15);
  const int brow = wc * 64 + (l & 15);
  f32x4 acc[4][4];
  #pragma unroll
  for (int mi = 0; mi < 4; mi++)
    #pragma unroll
    for (int ni = 0; ni < 4; ni++) { f32x4 z = {0.f, 0.f, 0.f, 0.f}; acc[mi][ni] = z; }

  for (int kt = 0; kt < K; kt += 32) {
    uint4 a0 = *(const uint4*)(Ap + kt);
    uint4 a1 = *(const uint4*)(Ap + kt + 8);
    *(uint4*)(As + ((sByte)      ^ sSwz)) = a0;
    *(uint4*)(As + ((sByte + 16) ^ sSwz)) = a1;
    if constexpr (BW == 0) {
      float4 f0 = *(const float4*)(Bp32 + kt);
      float4 f1 = *(const float4*)(Bp32 + kt + 4);
      float4 f2 = *(const float4*)(Bp32 + kt + 8);
      float4 f3 = *(const float4*)(Bp32 + kt + 12);
      us8 q0, q1;
      q0[0]=f2b(f0.x); q0[1]=f2b(f0.y); q0[2]=f2b(f0.z); q0[3]=f2b(f0.w);
      q0[4]=f2b(f1.x); q0[5]=f2b(f1.y); q0[6]=f2b(f1.z); q0[7]=f2b(f1.w);
      q1[0]=f2b(f2.x); q1[1]=f2b(f2.y); q1[2]=f2b(f2.z); q1[3]=f2b(f2.w);
      q1[4]=f2b(f3.x); q1[5]=f2b(f3.y); q1[6]=f2b(f3.z); q1[7]=f2b(f3.w);
      *(us8*)(Bs + ((sByte)      ^ sSwz)) = q0;
      *(us8*)(Bs + ((sByte + 16) ^ sSwz)) = q1;
    } else {
      uint4 b0 = *(const uint4*)(Bp16 + kt);
      uint4 b1 = *(const uint4*)(Bp16 + kt + 8);
      *(uint4*)(Bs + ((sByte)      ^ sSwz)) = b0;
      *(uint4*)(Bs + ((sByte + 16) ^ sSwz)) = b1;
    }
    __syncthreads();
    bf16x8 af[4], bfr[4];
    #pragma unroll
    for (int i = 0; i < 4; i++) {
      af[i]  = *(const bf16x8*)(As + (arow + 16 * i) * 64 + kOff);
      bfr[i] = *(const bf16x8*)(Bs + (brow + 16 * i) * 64 + kOff);
    }
    #pragma unroll
    for (int mi = 0; mi < 4; mi++)
      #pragma unroll
      for (int ni = 0; ni < 4; ni++)
        acc[mi][ni] = __builtin_amdgcn_mfma_f32_16x16x32_bf16(af[mi], bfr[ni], acc[mi][ni], 0, 0, 0);
    __syncthreads();
  }
  const int rbase = (l >> 4) << 2;
  const int cl = l & 15;
  #pragma unroll
  for (int mi = 0; mi < 4; mi++) {
    #pragma unroll
    for (int ni = 0; ni < 4; ni++) {
      #pragma unroll
      for (int rr = 0; rr < 4; rr++) {
        int row = m0 + wr * 64 + mi * 16 + rbase + rr;
        int col = n0 + wc * 64 + ni * 16 + cl;
        size_t idx = (size_t)row * N + col;
        float val = acc[mi][ni][rr];
        if constexpr (MODE == 0) Cf[idx] = val;
        if constexpr (MODE == 1) Cf[idx] = val + Res[idx];
        if constexpr (MODE == 2) Cb[idx] = f2b(val);
        if constexpr (MODE == 3) {
          float gv = b2f(Gaux[idx]);
          val *= gv / (1.0f + __expf(-gv));
          Cb[idx] = f2b(val);
        }
      }
    }
  }
}

// ---------------- LoRA ----------------
__global__ void k_lora_down(const unsigned short* __restrict__ h, const float* __restrict__ Am,
                            float* __restrict__ tb) {
  int t = threadIdx.x;
  int m = blockIdx.x * 16 + (t >> 4), r = t & 15;
  const unsigned short* hr = h + (size_t)m * DMODEL;
  const float* ar = Am + (size_t)r * DMODEL;
  float acc = 0.f;
  for (int d = 0; d < DMODEL; d += 4) {
    ushort4 hv = *(const ushort4*)(hr + d);
    float4 av = *(const float4*)(ar + d);
    acc += b2f(hv.x)*av.x + b2f(hv.y)*av.y + b2f(hv.z)*av.z + b2f(hv.w)*av.w;
  }
  tb[(size_t)m * RLORA + r] = acc;
}

__global__ void k_lora_up(const float* __restrict__ tb, const float* __restrict__ Bm,
                          float* __restrict__ out) {
  int tid = blockIdx.x * 256 + threadIdx.x;
  int m = tid >> 11, e = tid & (DMODEL - 1);
  const float* tr = tb + (size_t)m * RLORA;
  const float* br = Bm + (size_t)e * RLORA;
  float acc = 0.f;
  #pragma unroll
  for (int r = 0; r < RLORA; r += 4) {
    float4 tv = *(const float4*)(tr + r);
    float4 bv = *(const float4*)(br + r);
    acc += tv.x*bv.x + tv.y*bv.y + tv.z*bv.z + tv.w*bv.w;
  }
  out[tid] += 2.0f * acc;                      // ALPHA_OVER_R = 32/16
}

// ---------------- RoPE ----------------
__global__ void k_rope_table(float* __restrict__ ct, float* __restrict__ st) {
  int tid = blockIdx.x * 256 + threadIdx.x;
  int s = tid >> 6, i = tid & 63;
  float inv = __expf(-((float)i / 64.0f) * logf(10000.0f));
  float ang = (float)s * inv;
  ct[tid] = cosf(ang);
  st[tid] = sinf(ang);
}

__global__ void k_rope(float* __restrict__ q, float* __restrict__ k,
                       const float* __restrict__ ct, const float* __restrict__ st) {
  int tid = blockIdx.x * 256 + threadIdx.x;
  int i = tid & 63;
  int hh = (tid >> 6) & (NHEAD - 1);
  int s = (tid >> 10) & (SEQLEN - 1);
  int b = tid >> 20;
  size_t base = (((size_t)(b * SEQLEN + s)) * NHEAD + hh) * HEADD;
  float c = ct[s * 64 + i], sn = st[s * 64 + i];
  float q0 = q[base + i], q1 = q[base + i + 64];
  q[base + i]      = q0 * c - q1 * sn;
  q[base + i + 64] = q1 * c + q0 * sn;
  float k0 = k[base + i], k1 = k[base + i + 64];
  k[base + i]      = k0 * c - k1 * sn;
  k[base + i + 64] = k1 * c + k0 * sn;
}

// ---------------- fused causal attention, MFMA bf16 ----------------
// 64-row Q-tile per block, 4 waves x 16 q-rows; K-blocks of 64, causal-trimmed.
__global__ __launch_bounds__(256, 2)
void k_attn_mfma(const float* __restrict__ q, const float* __restrict__ k,
                 const float* __restrict__ v, const int* __restrict__ am,
                 unsigned short* __restrict__ o) {
  __shared__ unsigned char Kls[64 * 256];   // [n][128d] bf16, swz (n&7)<<4
  __shared__ unsigned char Vls[128 * 128];  // [d][64n] bf16 (transposed), swz vswz(d)
  __shared__ unsigned char Pls[64 * 128];   // [q][64n] bf16, swz (q&7)<<4
  const int qt = blockIdx.x, hh = blockIdx.y, b = blockIdx.z;
  const int t = threadIdx.x, l = t & 63, w = t >> 6;
  const int cl = l & 15, lh = l >> 4;
  const int rbase = lh << 2;

  // stage Q into Kls (bf16, swizzled), read per-wave A-frags into registers
  for (int ii = 0; ii < 8; ii++) {
    int row = (t >> 5) + 8 * ii, c = t & 31;
    float4 f = *(const float4*)(q + ((((size_t)b*SEQLEN + qt*64 + row)*NHEAD + hh) << 7) + c*4);
    ushort4 u; u.x=f2b(f.x); u.y=f2b(f.y); u.z=f2b(f.z); u.w=f2b(f.w);
    *(ushort4*)(Kls + ((row*256 + c*8) ^ ((row & 7) << 4))) = u;
  }
  __syncthreads();
  bf16x8 qf[4];
  {
    int row = w*16 + cl;
    int swz = (row & 7) << 4;
    #pragma unroll
    for (int kt = 0; kt < 4; kt++)
      qf[kt] = *(const bf16x8*)(Kls + ((row*256 + kt*64 + lh*16) ^ swz));
  }

  f32x4 oacc[8];
  #pragma unroll
  for (int i = 0; i < 8; i++) { f32x4 z = {0.f,0.f,0.f,0.f}; oacc[i] = z; }
  float mrun[4], lrun[4];
  #pragma unroll
  for (int r = 0; r < 4; r++) { mrun[r] = -3e38f; lrun[r] = 0.f; }

  for (int kb = 0; kb <= qt; kb++) {
    __syncthreads();                          // prior reads of Kls/Vls complete
    // stage K tile [64][128]
    for (int ii = 0; ii < 8; ii++) {
      int row = (t >> 5) + 8 * ii, c = t & 31;
      float4 f = *(const float4*)(k + ((((size_t)b*SEQLEN + kb*64 + row)*NHEAD + hh) << 7) + c*4);
      ushort4 u; u.x=f2b(f.x); u.y=f2b(f.y); u.z=f2b(f.z); u.w=f2b(f.w);
      *(ushort4*)(Kls + ((row*256 + c*8) ^ ((row & 7) << 4))) = u;
    }
    // stage V transposed [128][64] via lane-pair exchange
    for (int ii = 0; ii < 8; ii++) {
      int n = 2*w + 8*ii + (l >> 5);
      int d = (l & 31) * 4;
      float4 f = *(const float4*)(v + ((((size_t)b*SEQLEN + kb*64 + n)*NHEAD + hh) << 7) + d);
      float px = __shfl_xor(f.x, 32), py = __shfl_xor(f.y, 32),
            pz = __shfl_xor(f.z, 32), pw = __shfl_xor(f.w, 32);
      if (l < 32) {
        unsigned int w0 = (unsigned)f2b(f.x) | ((unsigned)f2b(px) << 16);
        unsigned int w1 = (unsigned)f2b(f.y) | ((unsigned)f2b(py) << 16);
        unsigned int w2 = (unsigned)f2b(f.z) | ((unsigned)f2b(pz) << 16);
        unsigned int w3 = (unsigned)f2b(f.w) | ((unsigned)f2b(pw) << 16);
        *(unsigned int*)(Vls + (((d+0)*128 + n*2) ^ vswz(d+0))) = w0;
        *(unsigned int*)(Vls + (((d+1)*128 + n*2) ^ vswz(d+1))) = w1;
        *(unsigned int*)(Vls + (((d+2)*128 + n*2) ^ vswz(d+2))) = w2;
        *(unsigned int*)(Vls + (((d+3)*128 + n*2) ^ vswz(d+3))) = w3;
      }
    }
    __syncthreads();
    // S = Q K^T (16 MFMA), C/D: col=cl, row=rbase+reg
    f32x4 sacc[4];
    #pragma unroll
    for (int nt = 0; nt < 4; nt++) { f32x4 z = {0.f,0.f,0.f,0.f}; sacc[nt] = z; }
    #pragma unroll
    for (int kt = 0; kt < 4; kt++) {
      #pragma unroll
      for (int nt = 0; nt < 4; nt++) {
        int row = nt*16 + cl;
        bf16x8 kf = *(const bf16x8*)(Kls + ((row*256 + kt*64 + lh*16) ^ ((row & 7) << 4)));
        sacc[nt] = __builtin_amdgcn_mfma_f32_16x16x32_bf16(qf[kt], kf, sacc[nt], 0, 0, 0);
      }
    }
    // online softmax (rows live in 16-lane groups; reduce over low-4 lane bits)
    float p[4][4];
    float mt[4] = {-3e38f, -3e38f, -3e38f, -3e38f};
    #pragma unroll
    for (int nt = 0; nt < 4; nt++) {
      int kg = kb*64 + nt*16 + cl;
      float pad = (1.0f - (float)am[b*SEQLEN + kg]) * (-1e9f);
      #pragma unroll
      for (int r = 0; r < 4; r++) {
        int qg = qt*64 + w*16 + rbase + r;
        float s = sacc[nt][r] * 0.08838834764831845f + pad;
        if (kg > qg) s = -1e30f;              // no-op for kb<qt
        p[nt][r] = s;
        mt[r] = fmaxf(mt[r], s);
      }
    }
    #pragma unroll
    for (int r = 0; r < 4; r++) {
      float m = mt[r];
      m = fmaxf(m, __shfl_xor(m, 1)); m = fmaxf(m, __shfl_xor(m, 2));
      m = fmaxf(m, __shfl_xor(m, 4)); m = fmaxf(m, __shfl_xor(m, 8));
      mt[r] = m;
    }
    float corr[4];
    #pragma unroll
    for (int r = 0; r < 4; r++) {
      float mnew = fmaxf(mrun[r], mt[r]);
      corr[r] = __expf(mrun[r] - mnew);
      mrun[r] = mnew;
    }
    float ps[4] = {0.f, 0.f, 0.f, 0.f};
    #pragma unroll
    for (int nt = 0; nt < 4; nt++)
      #pragma unroll
      for (int r = 0; r < 4; r++) {
        p[nt][r] = __expf(p[nt][r] - mrun[r]);
        ps[r] += p[nt][r];
      }
    #pragma unroll
    for (int r = 0; r < 4; r++) {
      float s = ps[r];
      s += __shfl_xor(s, 1); s += __shfl_xor(s, 2);
      s += __shfl_xor(s, 4); s += __shfl_xor(s, 8);
      lrun[r] = lrun[r] * corr[r] + s;
    }
    // write P tile (own wave's rows only; intra-wave LDS ordering suffices)
    #pragma unroll
    for (int nt = 0; nt < 4; nt++)
      #pragma unroll
      for (int r = 0; r < 4; r++) {
        int row = w*16 + rbase + r;
        *(unsigned short*)(Pls + ((row*128 + (nt*16 + cl)*2) ^ ((row & 7) << 4))) = f2b(p[nt][r]);
      }
    // rescale O
    #pragma unroll
    for (int dt = 0; dt < 8; dt++)
      #pragma unroll
      for (int r = 0; r < 4; r++) oacc[dt][r] *= corr[r];
    // PV (16 MFMA): A=P rows (own wave), B=V^T rows (d)
    {
      int prow = w*16 + cl, pswz = (prow & 7) << 4;
      bf16x8 pf0 = *(const bf16x8*)(Pls + ((prow*128 +  0 + lh*16) ^ pswz));
      bf16x8 pf1 = *(const bf16x8*)(Pls + ((prow*128 + 64 + lh*16) ^ pswz));
      #pragma unroll
      for (int dt = 0; dt < 8; dt++) {
        int drow = dt*16 + cl;
        bf16x8 vf0 = *(const bf16x8*)(Vls + ((drow*128 +  0 + lh*16) ^ vswz(drow)));
        bf16x8 vf1 = *(const bf16x8*)(Vls + ((drow*128 + 64 + lh*16) ^ vswz(drow)));
        oacc[dt] = __builtin_amdgcn_mfma_f32_16x16x32_bf16(pf0, vf0, oacc[dt], 0, 0, 0);
        oacc[dt] = __builtin_amdgcn_mfma_f32_16x16x32_bf16(pf1, vf1, oacc[dt], 0, 0, 0);
      }
    }
  }
  // write O (bf16), normalize by lrun
  size_t obase = (((size_t)b*SEQLEN + qt*64 + w*16) * NHEAD + hh) * HEADD;
  #pragma unroll
  for (int r = 0; r < 4; r++) {
    float inv = 1.0f / lrun[r];
    int row = rbase + r;
    #pragma unroll
    for (int dt = 0; dt < 8; dt++)
      o[obase + (size_t)row * (NHEAD*HEADD) + dt*16 + cl] = f2b(oacc[dt][r] * inv);
  }
}

// ---------------- pooling + final RMS ----------------
__global__ void k_pool(const float* __restrict__ x, const int* __restrict__ am,
                       const float* __restrict__ fn, float* __restrict__ pooled) {
  int b = blockIdx.x, t = threadIdx.x;
  __shared__ float red[4];
  float fc = 0.f;
  for (int i = t; i < SEQLEN; i += 256) fc += (float)am[b * SEQLEN + i];
  for (int m = 32; m; m >>= 1) fc += __shfl_xor(fc, m);
  if ((t & 63) == 0) red[t >> 6] = fc;
  __syncthreads();
  int idx = (int)(red[0] + red[1] + red[2] + red[3]) - 1;
  const float* xr = x + ((size_t)b * SEQLEN + idx) * DMODEL;
  float4 a = ((const float4*)xr)[t], c = ((const float4*)xr)[t + 256];
  float ss = a.x*a.x + a.y*a.y + a.z*a.z + a.w*a.w
           + c.x*c.x + c.y*c.y + c.z*c.z + c.w*c.w;
  for (int m = 32; m; m >>= 1) ss += __shfl_xor(ss, m);
  __syncthreads();
  if ((t & 63) == 0) red[t >> 6] = ss;
  __syncthreads();
  ss = red[0] + red[1] + red[2] + red[3];
  float rs = rsqrtf(ss * (1.0f / DMODEL) + 1e-5f);
  float4 w0 = ((const float4*)fn)[t], w1 = ((const float4*)fn)[t + 256];
  float4 o0, o1;
  o0.x = a.x*rs*w0.x; o0.y = a.y*rs*w0.y; o0.z = a.z*rs*w0.z; o0.w = a.w*rs*w0.w;
  o1.x = c.x*rs*w1.x; o1.y = c.y*rs*w1.y; o1.z = c.z*rs*w1.z; o1.w = c.w*rs*w1.w;
  ((float4*)(pooled + (size_t)b * DMODEL))[t] = o0;
  ((float4*)(pooled + (size_t)b * DMODEL))[t + 256] = o1;
}

// ---------------- classification head ----------------
__global__ void k_head1(const float* __restrict__ pooled, const float* __restrict__ W1,
                        const float* __restrict__ b1, float* __restrict__ h1) {
  int bi = blockIdx.x;
  int b = bi >> 3, e = ((bi & 7) << 8) + threadIdx.x;
  const float* pr = pooled + (size_t)b * DMODEL;
  const float* wr = W1 + (size_t)e * DMODEL;
  float acc = 0.f;
  for (int d = 0; d < DMODEL; d += 4) {
    float4 pv = *(const float4*)(pr + d);
    float4 wv = *(const float4*)(wr + d);
    acc += pv.x*wv.x + pv.y*wv.y + pv.z*wv.z + pv.w*wv.w;
  }
  h1[(size_t)b * DMODEL + e] = tanhf(acc + b1[e]);
}

__global__ void k_head2(const float* __restrict__ h1, const float* __restrict__ W2,
                        const float* __restrict__ b2, float* __restrict__ out) {
  int bi = blockIdx.x;
  int b = bi / 3, c = bi % 3;
  int l = threadIdx.x;
  float acc = 0.f;
  for (int e = l; e < DMODEL; e += 64)
    acc += h1[(size_t)b * DMODEL + e] * W2[(size_t)c * DMODEL + e];
  for (int m = 32; m; m >>= 1) acc += __shfl_xor(acc, m);
  if (l == 0) out[b * 3 + c] = acc + b2[c];
}

__global__ void k_sentinel(float* out) {
  if (threadIdx.x < 6) out[threadIdx.x] = -12345.0f;
}

// ---------------- launch ----------------
typedef void (*gemm_t)(const unsigned short*, const void*, float*, unsigned short*,
                       const float*, const unsigned short*, int, int);

extern "C" void kernel_launch(void* const* d_in, const int* in_sizes, int n_in,
                              void* d_out, int out_size, void* d_ws, size_t ws_size,
                              hipStream_t stream) {
  const int*   ids = (const int*)d_in[0];
  const int*   am  = (const int*)d_in[1];
  const float* emb = (const float*)d_in[2];
  const float* Wq  = (const float*)d_in[3];
  const float* Wk  = (const float*)d_in[4];
  const float* Wv  = (const float*)d_in[5];
  const float* Wo  = (const float*)d_in[6];
  const float* Aq  = (const float*)d_in[7];
  const float* Bq  = (const float*)d_in[8];
  const float* Av  = (const float*)d_in[9];
  const float* Bv  = (const float*)d_in[10];
  const float* Wg  = (const float*)d_in[11];
  const float* Wu  = (const float*)d_in[12];
  const float* Wd  = (const float*)d_in[13];
  const float* n1  = (const float*)d_in[14];
  const float* n2  = (const float*)d_in[15];
  const float* fn  = (const float*)d_in[16];
  const float* hW1 = (const float*)d_in[17];
  const float* hb1 = (const float*)d_in[18];
  const float* hW2 = (const float*)d_in[19];
  const float* hb2 = (const float*)d_in[20];
  float* out = (float*)d_out;

  const size_t XOFF = 0;
  const size_t HOFF = 16777216;
  const size_t ROFF = 25165824;
  const size_t RSZ  = 67108864;
  const size_t TOFF = ROFF + RSZ;
  const size_t NEED = TOFF + 131072 + 262144 + 262144 + 16384 + 16384;
  if (ws_size < NEED) {
    k_sentinel<<<1, 64, 0, stream>>>(out);
    return;
  }
  const size_t W16OFF   = (NEED + 255) & ~(size_t)255;
  const size_t W16BYTES = 536870912ull;            // 268.4M bf16 elems
  const bool   use16    = ws_size >= W16OFF + W16BYTES;

  char* ws = (char*)d_ws;
  float*          x   = (float*)(ws + XOFF);
  unsigned short* h   = (unsigned short*)(ws + HOFF);
  float*          q   = (float*)(ws + ROFF);
  float*          k   = (float*)(ws + ROFF + 16777216);
  float*          v   = (float*)(ws + ROFF + 33554432);
  unsigned short* o   = (unsigned short*)(ws + ROFF + 50331648);
  unsigned short* g   = (unsigned short*)(ws + ROFF);
  unsigned short* act = (unsigned short*)(ws + ROFF + 33554432);
  float* tb     = (float*)(ws + TOFF);
  float* ct     = (float*)(ws + TOFF + 131072);
  float* st     = (float*)(ws + TOFF + 131072 + 262144);
  float* pooled = (float*)(ws + TOFF + 131072 + 524288);
  float* h1     = (float*)(ws + TOFF + 131072 + 524288 + 16384);

  unsigned short* w16 = (unsigned short*)(ws + W16OFF);
  const size_t QS = 4ull * DMODEL * DMODEL;        // per-tensor elems (QKVO, all layers)
  const size_t FS = 4ull * FFDIM * DMODEL;
  unsigned short *wq16 = w16,            *wk16 = w16 + QS,     *wv16 = w16 + 2*QS,
                 *wo16 = w16 + 3*QS,     *wg16 = w16 + 4*QS,   *wu16 = w16 + 4*QS + FS,
                 *wd16 = w16 + 4*QS + 2*FS;
  if (use16) {
    k_cvt16<<<2048, 256, 0, stream>>>(Wq, wq16, (int)(QS / 8));
    k_cvt16<<<2048, 256, 0, stream>>>(Wk, wk16, (int)(QS / 8));
    k_cvt16<<<2048, 256, 0, stream>>>(Wv, wv16, (int)(QS / 8));
    k_cvt16<<<2048, 256, 0, stream>>>(Wo, wo16, (int)(QS / 8));
    k_cvt16<<<2048, 256, 0, stream>>>(Wg, wg16, (int)(FS / 8));
    k_cvt16<<<2048, 256, 0, stream>>>(Wu, wu16, (int)(FS / 8));
    k_cvt16<<<2048, 256, 0, stream>>>(Wd, wd16, (int)(FS / 8));
  }
  gemm_t G0 = use16 ? (gemm_t)k_gemm<0,1> : (gemm_t)k_gemm<0,0>;
  gemm_t G1 = use16 ? (gemm_t)k_gemm<1,1> : (gemm_t)k_gemm<1,0>;
  gemm_t G2 = use16 ? (gemm_t)k_gemm<2,1> : (gemm_t)k_gemm<2,0>;
  gemm_t G3 = use16 ? (gemm_t)k_gemm<3,1> : (gemm_t)k_gemm<3,0>;

  k_embed<<<NTOK, 256, 0, stream>>>(ids, emb, x);
  k_rope_table<<<SEQLEN * 64 / 256, 256, 0, stream>>>(ct, st);

  dim3 g16(16, 16), g64(64, 16), ga(SEQLEN / 64, NHEAD, NBATCH);
  const size_t DD = (size_t)DMODEL * DMODEL, FD = (size_t)FFDIM * DMODEL;
  for (int lay = 0; lay < NLAYER; lay++) {
    const void* wqB = use16 ? (const void*)(wq16 + lay*DD) : (const void*)(Wq + lay*DD);
    const void* wkB = use16 ? (const void*)(wk16 + lay*DD) : (const void*)(Wk + lay*DD);
    const void* wvB = use16 ? (const void*)(wv16 + lay*DD) : (const void*)(Wv + lay*DD);
    const void* woB = use16 ? (const void*)(wo16 + lay*DD) : (const void*)(Wo + lay*DD);
    const void* wgB = use16 ? (const void*)(wg16 + lay*FD) : (const void*)(Wg + lay*FD);
    const void* wuB = use16 ? (const void*)(wu16 + lay*FD) : (const void*)(Wu + lay*FD);
    const void* wdB = use16 ? (const void*)(wd16 + lay*FD) : (const void*)(Wd + lay*FD);

    k_rmsnorm<<<NTOK, 256, 0, stream>>>(x, n1 + (size_t)lay * DMODEL, h);
    G0<<<g16, 256, 0, stream>>>(h, wqB, q, nullptr, nullptr, nullptr, DMODEL, DMODEL);
    G0<<<g16, 256, 0, stream>>>(h, wkB, k, nullptr, nullptr, nullptr, DMODEL, DMODEL);
    G0<<<g16, 256, 0, stream>>>(h, wvB, v, nullptr, nullptr, nullptr, DMODEL, DMODEL);
    k_lora_down<<<NTOK / 16, 256, 0, stream>>>(h, Aq + (size_t)lay * RLORA * DMODEL, tb);
    k_lora_up<<<NTOK * DMODEL / 256, 256, 0, stream>>>(tb, Bq + (size_t)lay * DMODEL * RLORA, q);
    k_lora_down<<<NTOK / 16, 256, 0, stream>>>(h, Av + (size_t)lay * RLORA * DMODEL, tb);
    k_lora_up<<<NTOK * DMODEL / 256, 256, 0, stream>>>(tb, Bv + (size_t)lay * DMODEL * RLORA, v);
    k_rope<<<NBATCH * SEQLEN * NHEAD * 64 / 256, 256, 0, stream>>>(q, k, ct, st);
    k_attn_mfma<<<ga, 256, 0, stream>>>(q, k, v, am, o);
    G1<<<g16, 256, 0, stream>>>(o, woB, x, nullptr, x, nullptr, DMODEL, DMODEL);
    k_rmsnorm<<<NTOK, 256, 0, stream>>>(x, n2 + (size_t)lay * DMODEL, h);
    G2<<<g64, 256, 0, stream>>>(h, wgB, nullptr, g, nullptr, nullptr, FFDIM, DMODEL);
    G3<<<g64, 256, 0, stream>>>(h, wuB, nullptr, act, nullptr, g, FFDIM, DMODEL);
    G1<<<g16, 256, 0, stream>>>(act, wdB, x, nullptr, x, nullptr, DMODEL, FFDIM);
  }
  k_pool<<<NBATCH, 256, 0, stream>>>(x, am, fn, pooled);
  k_head1<<<16, 256, 0, stream>>>(pooled, hW1, hb1, h1);
  k_head2<<<6, 64, 0, stream>>>(h1, hW2, hb2, out);
}

// Round 3
// 3816.668 us; speedup vs baseline: 1.9570x; 1.1298x over previous
//
#include <hip/hip_runtime.h>

// ---------------- model constants ----------------
#define NLAYER 4
#define DMODEL 2048
#define NHEAD  16
#define HEADD  128
#define FFDIM  8192
#define RLORA  16
#define SEQLEN 1024
#define NBATCH 2
#define NTOK   (NBATCH*SEQLEN)   // 2048

typedef __bf16 bf16x8 __attribute__((ext_vector_type(8)));
typedef float  f32x4  __attribute__((ext_vector_type(4)));
typedef unsigned short us8 __attribute__((ext_vector_type(8)));

__device__ __forceinline__ unsigned short f2b(float f) {
  unsigned int u = __builtin_bit_cast(unsigned int, f);
  u += 0x7FFFu + ((u >> 16) & 1u);          // round-to-nearest-even
  return (unsigned short)(u >> 16);
}
__device__ __forceinline__ float b2f(unsigned short s) {
  unsigned int u = ((unsigned int)s) << 16;
  return __builtin_bit_cast(float, u);
}
// V-LDS swizzle for attention
__device__ __forceinline__ int vswz(int d) {
  return (((d >> 2) & 7) ^ ((d & 3) << 1)) << 4;
}
// async global->LDS, 16B per lane; lds dest wave-uniform (lane*16 appended by HW)
typedef __attribute__((address_space(1))) const void* gas_t;
typedef __attribute__((address_space(3))) void* las_t;
__device__ __forceinline__ void gload16(const void* g, void* l) {
  __builtin_amdgcn_global_load_lds((gas_t)g, (las_t)l, 16, 0, 0);
}

// ---------------- embedding gather ----------------
__global__ void k_embed(const int* __restrict__ ids, const float* __restrict__ emb,
                        float* __restrict__ x) {
  int row = blockIdx.x;
  int id = ids[row];
  const float4* src = (const float4*)(emb + (size_t)id * DMODEL);
  float4* dst = (float4*)(x + (size_t)row * DMODEL);
  for (int i = threadIdx.x; i < DMODEL / 4; i += 256) dst[i] = src[i];
}

// ---------------- weight fp32 -> bf16 ----------------
__global__ void k_cvt16(const float* __restrict__ s, unsigned short* __restrict__ d, int n8) {
  int stride = gridDim.x * 256;
  for (int i = blockIdx.x * 256 + threadIdx.x; i < n8; i += stride) {
    size_t si = (size_t)i * 2;
    float4 a = ((const float4*)s)[si];
    float4 b = ((const float4*)s)[si + 1];
    us8 o;
    o[0]=f2b(a.x); o[1]=f2b(a.y); o[2]=f2b(a.z); o[3]=f2b(a.w);
    o[4]=f2b(b.x); o[5]=f2b(b.y); o[6]=f2b(b.z); o[7]=f2b(b.w);
    ((us8*)d)[i] = o;
  }
}

// ---------------- RMSNorm -> bf16 ----------------
__global__ void k_rmsnorm(const float* __restrict__ x, const float* __restrict__ w,
                          unsigned short* __restrict__ h) {
  int row = blockIdx.x, t = threadIdx.x;
  const float* xr = x + (size_t)row * DMODEL;
  float4 a = ((const float4*)xr)[t];
  float4 b = ((const float4*)xr)[t + 256];
  float ss = a.x*a.x + a.y*a.y + a.z*a.z + a.w*a.w
           + b.x*b.x + b.y*b.y + b.z*b.z + b.w*b.w;
  for (int m = 32; m; m >>= 1) ss += __shfl_xor(ss, m);
  __shared__ float red[4];
  if ((t & 63) == 0) red[t >> 6] = ss;
  __syncthreads();
  ss = red[0] + red[1] + red[2] + red[3];
  float rs = rsqrtf(ss * (1.0f / DMODEL) + 1e-5f);
  float4 wa = ((const float4*)w)[t];
  float4 wb = ((const float4*)w)[t + 256];
  ushort4 oa, ob;
  oa.x = f2b(a.x * wa.x * rs); oa.y = f2b(a.y * wa.y * rs);
  oa.z = f2b(a.z * wa.z * rs); oa.w = f2b(a.w * wa.w * rs);
  ob.x = f2b(b.x * wb.x * rs); ob.y = f2b(b.y * wb.y * rs);
  ob.z = f2b(b.z * wb.z * rs); ob.w = f2b(b.w * wb.w * rs);
  ushort4* hr = (ushort4*)(h + (size_t)row * DMODEL);
  hr[t] = oa;
  hr[t + 256] = ob;
}

// ---------------- NT GEMM fast path (bf16 A and B), m97 structure ----------------
// global_load_lds(16B) staging, linear LDS dest + source-side XOR swizzle
// f(row)=(row>>1)&3 over 16B slots; ds_read applies same swizzle -> 2-way (free).
// MODE 0: Cf=acc; 1: Cf=acc+Res; 2: Cb=bf16(acc); 3: Cb=bf16(silu(Gaux)*acc)
template<int MODE>
__global__ __launch_bounds__(256, 2)
void k_gemm2(const unsigned short* __restrict__ A, const void* __restrict__ Bv,
             float* __restrict__ Cf, unsigned short* __restrict__ Cb,
             const float* __restrict__ Res, const unsigned short* __restrict__ Gaux,
             int N, int K) {
  __shared__ unsigned short As[128 * 32];
  __shared__ unsigned short Bs[128 * 32];
  const unsigned short* B = (const unsigned short*)Bv;
  const int t = threadIdx.x, l = t & 63, w = t >> 6;
  const int wr = w >> 1, wc = w & 1;
  // XCD-aware block swizzle (nwg % 8 == 0 for all our grids)
  const int nbx = gridDim.x;
  const int nwg = nbx * gridDim.y;
  const int bid = blockIdx.y * nbx + blockIdx.x;
  const int cpx = nwg >> 3;
  const int sid = (bid & 7) * cpx + (bid >> 3);
  const int m0 = (sid / nbx) << 7, n0 = (sid % nbx) << 7;
  // staging source: lane-constant swizzled column offset (elems)
  const int gcol = 8 * ((l & 3) ^ ((l >> 3) & 3));
  const int srow = (w << 5) + (l >> 2);            // wave rows 32w..32w+31
  const unsigned short* Ag = A + (size_t)(m0 + srow) * K + gcol;
  const unsigned short* Bg = B + (size_t)(n0 + srow) * K + gcol;
  const size_t rowK16 = (size_t)16 * K;
  unsigned short* AsW = As + (w << 10);            // 32w rows * 32 elems
  unsigned short* BsW = Bs + (w << 10);
  // fragment read: lane-constant swizzled 16B slot
  const int kOff = (((l >> 4) ^ ((l >> 1) & 3)) << 4);
  const int aByte = (wr * 64 + (l & 15)) * 64 + kOff;
  const int bByte = (wc * 64 + (l & 15)) * 64 + kOff;
  f32x4 acc[4][4];
  #pragma unroll
  for (int mi = 0; mi < 4; mi++)
    #pragma unroll
    for (int ni = 0; ni < 4; ni++) { f32x4 z = {0.f, 0.f, 0.f, 0.f}; acc[mi][ni] = z; }

  for (int kt = 0; kt < K; kt += 32) {
    gload16(Ag + kt,          AsW);
    gload16(Ag + kt + rowK16, AsW + 512);
    gload16(Bg + kt,          BsW);
    gload16(Bg + kt + rowK16, BsW + 512);
    __syncthreads();                                // drains vmcnt(0) pre-barrier
    bf16x8 af[4], bf[4];
    #pragma unroll
    for (int i = 0; i < 4; i++) {
      af[i] = *(const bf16x8*)((const char*)As + aByte + i * 1024);
      bf[i] = *(const bf16x8*)((const char*)Bs + bByte + i * 1024);
    }
    #pragma unroll
    for (int mi = 0; mi < 4; mi++)
      #pragma unroll
      for (int ni = 0; ni < 4; ni++)
        acc[mi][ni] = __builtin_amdgcn_mfma_f32_16x16x32_bf16(af[mi], bf[ni], acc[mi][ni], 0, 0, 0);
    __syncthreads();
  }
  const int rbase = (l >> 4) << 2;
  const int cl = l & 15;
  #pragma unroll
  for (int mi = 0; mi < 4; mi++) {
    #pragma unroll
    for (int ni = 0; ni < 4; ni++) {
      #pragma unroll
      for (int rr = 0; rr < 4; rr++) {
        int row = m0 + wr * 64 + mi * 16 + rbase + rr;
        int col = n0 + wc * 64 + ni * 16 + cl;
        size_t idx = (size_t)row * N + col;
        float val = acc[mi][ni][rr];
        if constexpr (MODE == 0) Cf[idx] = val;
        if constexpr (MODE == 1) Cf[idx] = val + Res[idx];
        if constexpr (MODE == 2) Cb[idx] = f2b(val);
        if constexpr (MODE == 3) {
          float gv = b2f(Gaux[idx]);
          val *= gv / (1.0f + __expf(-gv));
          Cb[idx] = f2b(val);
        }
      }
    }
  }
}

// ---------------- NT GEMM fallback (B fp32, reg-staged) ----------------
template<int MODE>
__global__ __launch_bounds__(256, 2)
void k_gemm(const unsigned short* __restrict__ A, const void* __restrict__ Bv,
            float* __restrict__ Cf, unsigned short* __restrict__ Cb,
            const float* __restrict__ Res, const unsigned short* __restrict__ Gaux,
            int N, int K) {
  __shared__ unsigned char lds[128 * 32 * 2 * 2];
  unsigned char* As = lds;
  unsigned char* Bs = lds + 128 * 32 * 2;
  const int t = threadIdx.x;
  const int l = t & 63, w = t >> 6;
  const int wr = w >> 1, wc = w & 1;
  const int m0 = blockIdx.y << 7, n0 = blockIdx.x << 7;
  const int sr = t >> 1, skh = (t & 1) << 4;
  const int sByte = sr * 64 + (skh << 1);
  const int sSwz = (sr & 3) << 4;
  const unsigned short* Ap = A + (size_t)(m0 + sr) * K + skh;
  const float* Bp32 = (const float*)Bv + (size_t)(n0 + sr) * K + skh;
  const int kOff = (((l >> 4) << 4)) ^ ((l & 3) << 4);
  const int arow = wr * 64 + (l & 15);
  const int brow = wc * 64 + (l & 15);
  f32x4 acc[4][4];
  #pragma unroll
  for (int mi = 0; mi < 4; mi++)
    #pragma unroll
    for (int ni = 0; ni < 4; ni++) { f32x4 z = {0.f, 0.f, 0.f, 0.f}; acc[mi][ni] = z; }

  for (int kt = 0; kt < K; kt += 32) {
    uint4 a0 = *(const uint4*)(Ap + kt);
    uint4 a1 = *(const uint4*)(Ap + kt + 8);
    *(uint4*)(As + ((sByte)      ^ sSwz)) = a0;
    *(uint4*)(As + ((sByte + 16) ^ sSwz)) = a1;
    float4 f0 = *(const float4*)(Bp32 + kt);
    float4 f1 = *(const float4*)(Bp32 + kt + 4);
    float4 f2 = *(const float4*)(Bp32 + kt + 8);
    float4 f3 = *(const float4*)(Bp32 + kt + 12);
    us8 q0, q1;
    q0[0]=f2b(f0.x); q0[1]=f2b(f0.y); q0[2]=f2b(f0.z); q0[3]=f2b(f0.w);
    q0[4]=f2b(f1.x); q0[5]=f2b(f1.y); q0[6]=f2b(f1.z); q0[7]=f2b(f1.w);
    q1[0]=f2b(f2.x); q1[1]=f2b(f2.y); q1[2]=f2b(f2.z); q1[3]=f2b(f2.w);
    q1[4]=f2b(f3.x); q1[5]=f2b(f3.y); q1[6]=f2b(f3.z); q1[7]=f2b(f3.w);
    *(us8*)(Bs + ((sByte)      ^ sSwz)) = q0;
    *(us8*)(Bs + ((sByte + 16) ^ sSwz)) = q1;
    __syncthreads();
    bf16x8 af[4], bfr[4];
    #pragma unroll
    for (int i = 0; i < 4; i++) {
      af[i]  = *(const bf16x8*)(As + (arow + 16 * i) * 64 + kOff);
      bfr[i] = *(const bf16x8*)(Bs + (brow + 16 * i) * 64 + kOff);
    }
    #pragma unroll
    for (int mi = 0; mi < 4; mi++)
      #pragma unroll
      for (int ni = 0; ni < 4; ni++)
        acc[mi][ni] = __builtin_amdgcn_mfma_f32_16x16x32_bf16(af[mi], bfr[ni], acc[mi][ni], 0, 0, 0);
    __syncthreads();
  }
  const int rbase = (l >> 4) << 2;
  const int cl = l & 15;
  #pragma unroll
  for (int mi = 0; mi < 4; mi++) {
    #pragma unroll
    for (int ni = 0; ni < 4; ni++) {
      #pragma unroll
      for (int rr = 0; rr < 4; rr++) {
        int row = m0 + wr * 64 + mi * 16 + rbase + rr;
        int col = n0 + wc * 64 + ni * 16 + cl;
        size_t idx = (size_t)row * N + col;
        float val = acc[mi][ni][rr];
        if constexpr (MODE == 0) Cf[idx] = val;
        if constexpr (MODE == 1) Cf[idx] = val + Res[idx];
        if constexpr (MODE == 2) Cb[idx] = f2b(val);
        if constexpr (MODE == 3) {
          float gv = b2f(Gaux[idx]);
          val *= gv / (1.0f + __expf(-gv));
          Cb[idx] = f2b(val);
        }
      }
    }
  }
}

// ---------------- LoRA ----------------
__global__ void k_lora_down(const unsigned short* __restrict__ h, const float* __restrict__ Am,
                            float* __restrict__ tb) {
  int t = threadIdx.x;
  int m = blockIdx.x * 16 + (t >> 4), r = t & 15;
  const unsigned short* hr = h + (size_t)m * DMODEL;
  const float* ar = Am + (size_t)r * DMODEL;
  float acc = 0.f;
  for (int d = 0; d < DMODEL; d += 4) {
    ushort4 hv = *(const ushort4*)(hr + d);
    float4 av = *(const float4*)(ar + d);
    acc += b2f(hv.x)*av.x + b2f(hv.y)*av.y + b2f(hv.z)*av.z + b2f(hv.w)*av.w;
  }
  tb[(size_t)m * RLORA + r] = acc;
}

__global__ void k_lora_up(const float* __restrict__ tb, const float* __restrict__ Bm,
                          float* __restrict__ out) {
  int tid = blockIdx.x * 256 + threadIdx.x;
  int m = tid >> 11, e = tid & (DMODEL - 1);
  const float* tr = tb + (size_t)m * RLORA;
  const float* br = Bm + (size_t)e * RLORA;
  float acc = 0.f;
  #pragma unroll
  for (int r = 0; r < RLORA; r += 4) {
    float4 tv = *(const float4*)(tr + r);
    float4 bv = *(const float4*)(br + r);
    acc += tv.x*bv.x + tv.y*bv.y + tv.z*bv.z + tv.w*bv.w;
  }
  out[tid] += 2.0f * acc;                      // ALPHA_OVER_R = 32/16
}

// ---------------- RoPE ----------------
__global__ void k_rope_table(float* __restrict__ ct, float* __restrict__ st) {
  int tid = blockIdx.x * 256 + threadIdx.x;
  int s = tid >> 6, i = tid & 63;
  float inv = __expf(-((float)i / 64.0f) * logf(10000.0f));
  float ang = (float)s * inv;
  ct[tid] = cosf(ang);
  st[tid] = sinf(ang);
}

__global__ void k_rope(float* __restrict__ q, float* __restrict__ k,
                       const float* __restrict__ ct, const float* __restrict__ st) {
  int tid = blockIdx.x * 256 + threadIdx.x;
  int i = tid & 63;
  int hh = (tid >> 6) & (NHEAD - 1);
  int s = (tid >> 10) & (SEQLEN - 1);
  int b = tid >> 20;
  size_t base = (((size_t)(b * SEQLEN + s)) * NHEAD + hh) * HEADD;
  float c = ct[s * 64 + i], sn = st[s * 64 + i];
  float q0 = q[base + i], q1 = q[base + i + 64];
  q[base + i]      = q0 * c - q1 * sn;
  q[base + i + 64] = q1 * c + q0 * sn;
  float k0 = k[base + i], k1 = k[base + i + 64];
  k[base + i]      = k0 * c - k1 * sn;
  k[base + i + 64] = k1 * c + k0 * sn;
}

// ---------------- fused causal attention, MFMA bf16 ----------------
__global__ __launch_bounds__(256, 2)
void k_attn_mfma(const float* __restrict__ q, const float* __restrict__ k,
                 const float* __restrict__ v, const int* __restrict__ am,
                 unsigned short* __restrict__ o) {
  __shared__ unsigned char Kls[64 * 256];
  __shared__ unsigned char Vls[128 * 128];
  __shared__ unsigned char Pls[64 * 128];
  const int qt = blockIdx.x, hh = blockIdx.y, b = blockIdx.z;
  const int t = threadIdx.x, l = t & 63, w = t >> 6;
  const int cl = l & 15, lh = l >> 4;
  const int rbase = lh << 2;

  for (int ii = 0; ii < 8; ii++) {
    int row = (t >> 5) + 8 * ii, c = t & 31;
    float4 f = *(const float4*)(q + ((((size_t)b*SEQLEN + qt*64 + row)*NHEAD + hh) << 7) + c*4);
    ushort4 u; u.x=f2b(f.x); u.y=f2b(f.y); u.z=f2b(f.z); u.w=f2b(f.w);
    *(ushort4*)(Kls + ((row*256 + c*8) ^ ((row & 7) << 4))) = u;
  }
  __syncthreads();
  bf16x8 qf[4];
  {
    int row = w*16 + cl;
    int swz = (row & 7) << 4;
    #pragma unroll
    for (int kt = 0; kt < 4; kt++)
      qf[kt] = *(const bf16x8*)(Kls + ((row*256 + kt*64 + lh*16) ^ swz));
  }

  f32x4 oacc[8];
  #pragma unroll
  for (int i = 0; i < 8; i++) { f32x4 z = {0.f,0.f,0.f,0.f}; oacc[i] = z; }
  float mrun[4], lrun[4];
  #pragma unroll
  for (int r = 0; r < 4; r++) { mrun[r] = -3e38f; lrun[r] = 0.f; }

  for (int kb = 0; kb <= qt; kb++) {
    __syncthreads();
    for (int ii = 0; ii < 8; ii++) {
      int row = (t >> 5) + 8 * ii, c = t & 31;
      float4 f = *(const float4*)(k + ((((size_t)b*SEQLEN + kb*64 + row)*NHEAD + hh) << 7) + c*4);
      ushort4 u; u.x=f2b(f.x); u.y=f2b(f.y); u.z=f2b(f.z); u.w=f2b(f.w);
      *(ushort4*)(Kls + ((row*256 + c*8) ^ ((row & 7) << 4))) = u;
    }
    for (int ii = 0; ii < 8; ii++) {
      int n = 2*w + 8*ii + (l >> 5);
      int d = (l & 31) * 4;
      float4 f = *(const float4*)(v + ((((size_t)b*SEQLEN + kb*64 + n)*NHEAD + hh) << 7) + d);
      float px = __shfl_xor(f.x, 32), py = __shfl_xor(f.y, 32),
            pz = __shfl_xor(f.z, 32), pw = __shfl_xor(f.w, 32);
      if (l < 32) {
        unsigned int w0 = (unsigned)f2b(f.x) | ((unsigned)f2b(px) << 16);
        unsigned int w1 = (unsigned)f2b(f.y) | ((unsigned)f2b(py) << 16);
        unsigned int w2 = (unsigned)f2b(f.z) | ((unsigned)f2b(pz) << 16);
        unsigned int w3 = (unsigned)f2b(f.w) | ((unsigned)f2b(pw) << 16);
        *(unsigned int*)(Vls + (((d+0)*128 + n*2) ^ vswz(d+0))) = w0;
        *(unsigned int*)(Vls + (((d+1)*128 + n*2) ^ vswz(d+1))) = w1;
        *(unsigned int*)(Vls + (((d+2)*128 + n*2) ^ vswz(d+2))) = w2;
        *(unsigned int*)(Vls + (((d+3)*128 + n*2) ^ vswz(d+3))) = w3;
      }
    }
    __syncthreads();
    f32x4 sacc[4];
    #pragma unroll
    for (int nt = 0; nt < 4; nt++) { f32x4 z = {0.f,0.f,0.f,0.f}; sacc[nt] = z; }
    #pragma unroll
    for (int kt = 0; kt < 4; kt++) {
      #pragma unroll
      for (int nt = 0; nt < 4; nt++) {
        int row = nt*16 + cl;
        bf16x8 kf = *(const bf16x8*)(Kls + ((row*256 + kt*64 + lh*16) ^ ((row & 7) << 4)));
        sacc[nt] = __builtin_amdgcn_mfma_f32_16x16x32_bf16(qf[kt], kf, sacc[nt], 0, 0, 0);
      }
    }
    float p[4][4];
    float mt[4] = {-3e38f, -3e38f, -3e38f, -3e38f};
    #pragma unroll
    for (int nt = 0; nt < 4; nt++) {
      int kg = kb*64 + nt*16 + cl;
      float pad = (1.0f - (float)am[b*SEQLEN + kg]) * (-1e9f);
      #pragma unroll
      for (int r = 0; r < 4; r++) {
        int qg = qt*64 + w*16 + rbase + r;
        float s = sacc[nt][r] * 0.08838834764831845f + pad;
        if (kg > qg) s = -1e30f;
        p[nt][r] = s;
        mt[r] = fmaxf(mt[r], s);
      }
    }
    #pragma unroll
    for (int r = 0; r < 4; r++) {
      float m = mt[r];
      m = fmaxf(m, __shfl_xor(m, 1)); m = fmaxf(m, __shfl_xor(m, 2));
      m = fmaxf(m, __shfl_xor(m, 4)); m = fmaxf(m, __shfl_xor(m, 8));
      mt[r] = m;
    }
    float corr[4];
    #pragma unroll
    for (int r = 0; r < 4; r++) {
      float mnew = fmaxf(mrun[r], mt[r]);
      corr[r] = __expf(mrun[r] - mnew);
      mrun[r] = mnew;
    }
    float ps[4] = {0.f, 0.f, 0.f, 0.f};
    #pragma unroll
    for (int nt = 0; nt < 4; nt++)
      #pragma unroll
      for (int r = 0; r < 4; r++) {
        p[nt][r] = __expf(p[nt][r] - mrun[r]);
        ps[r] += p[nt][r];
      }
    #pragma unroll
    for (int r = 0; r < 4; r++) {
      float s = ps[r];
      s += __shfl_xor(s, 1); s += __shfl_xor(s, 2);
      s += __shfl_xor(s, 4); s += __shfl_xor(s, 8);
      lrun[r] = lrun[r] * corr[r] + s;
    }
    #pragma unroll
    for (int nt = 0; nt < 4; nt++)
      #pragma unroll
      for (int r = 0; r < 4; r++) {
        int row = w*16 + rbase + r;
        *(unsigned short*)(Pls + ((row*128 + (nt*16 + cl)*2) ^ ((row & 7) << 4))) = f2b(p[nt][r]);
      }
    #pragma unroll
    for (int dt = 0; dt < 8; dt++)
      #pragma unroll
      for (int r = 0; r < 4; r++) oacc[dt][r] *= corr[r];
    {
      int prow = w*16 + cl, pswz = (prow & 7) << 4;
      bf16x8 pf0 = *(const bf16x8*)(Pls + ((prow*128 +  0 + lh*16) ^ pswz));
      bf16x8 pf1 = *(const bf16x8*)(Pls + ((prow*128 + 64 + lh*16) ^ pswz));
      #pragma unroll
      for (int dt = 0; dt < 8; dt++) {
        int drow = dt*16 + cl;
        bf16x8 vf0 = *(const bf16x8*)(Vls + ((drow*128 +  0 + lh*16) ^ vswz(drow)));
        bf16x8 vf1 = *(const bf16x8*)(Vls + ((drow*128 + 64 + lh*16) ^ vswz(drow)));
        oacc[dt] = __builtin_amdgcn_mfma_f32_16x16x32_bf16(pf0, vf0, oacc[dt], 0, 0, 0);
        oacc[dt] = __builtin_amdgcn_mfma_f32_16x16x32_bf16(pf1, vf1, oacc[dt], 0, 0, 0);
      }
    }
  }
  size_t obase = (((size_t)b*SEQLEN + qt*64 + w*16) * NHEAD + hh) * HEADD;
  #pragma unroll
  for (int r = 0; r < 4; r++) {
    float inv = 1.0f / lrun[r];
    int row = rbase + r;
    #pragma unroll
    for (int dt = 0; dt < 8; dt++)
      o[obase + (size_t)row * (NHEAD*HEADD) + dt*16 + cl] = f2b(oacc[dt][r] * inv);
  }
}

// ---------------- pooling + final RMS ----------------
__global__ void k_pool(const float* __restrict__ x, const int* __restrict__ am,
                       const float* __restrict__ fn, float* __restrict__ pooled) {
  int b = blockIdx.x, t = threadIdx.x;
  __shared__ float red[4];
  float fc = 0.f;
  for (int i = t; i < SEQLEN; i += 256) fc += (float)am[b * SEQLEN + i];
  for (int m = 32; m; m >>= 1) fc += __shfl_xor(fc, m);
  if ((t & 63) == 0) red[t >> 6] = fc;
  __syncthreads();
  int idx = (int)(red[0] + red[1] + red[2] + red[3]) - 1;
  const float* xr = x + ((size_t)b * SEQLEN + idx) * DMODEL;
  float4 a = ((const float4*)xr)[t], c = ((const float4*)xr)[t + 256];
  float ss = a.x*a.x + a.y*a.y + a.z*a.z + a.w*a.w
           + c.x*c.x + c.y*c.y + c.z*c.z + c.w*c.w;
  for (int m = 32; m; m >>= 1) ss += __shfl_xor(ss, m);
  __syncthreads();
  if ((t & 63) == 0) red[t >> 6] = ss;
  __syncthreads();
  ss = red[0] + red[1] + red[2] + red[3];
  float rs = rsqrtf(ss * (1.0f / DMODEL) + 1e-5f);
  float4 w0 = ((const float4*)fn)[t], w1 = ((const float4*)fn)[t + 256];
  float4 o0, o1;
  o0.x = a.x*rs*w0.x; o0.y = a.y*rs*w0.y; o0.z = a.z*rs*w0.z; o0.w = a.w*rs*w0.w;
  o1.x = c.x*rs*w1.x; o1.y = c.y*rs*w1.y; o1.z = c.z*rs*w1.z; o1.w = c.w*rs*w1.w;
  ((float4*)(pooled + (size_t)b * DMODEL))[t] = o0;
  ((float4*)(pooled + (size_t)b * DMODEL))[t + 256] = o1;
}

// ---------------- classification head ----------------
__global__ void k_head1(const float* __restrict__ pooled, const float* __restrict__ W1,
                        const float* __restrict__ b1, float* __restrict__ h1) {
  int bi = blockIdx.x;
  int b = bi >> 3, e = ((bi & 7) << 8) + threadIdx.x;
  const float* pr = pooled + (size_t)b * DMODEL;
  const float* wr = W1 + (size_t)e * DMODEL;
  float acc = 0.f;
  for (int d = 0; d < DMODEL; d += 4) {
    float4 pv = *(const float4*)(pr + d);
    float4 wv = *(const float4*)(wr + d);
    acc += pv.x*wv.x + pv.y*wv.y + pv.z*wv.z + pv.w*wv.w;
  }
  h1[(size_t)b * DMODEL + e] = tanhf(acc + b1[e]);
}

__global__ void k_head2(const float* __restrict__ h1, const float* __restrict__ W2,
                        const float* __restrict__ b2, float* __restrict__ out) {
  int bi = blockIdx.x;
  int b = bi / 3, c = bi % 3;
  int l = threadIdx.x;
  float acc = 0.f;
  for (int e = l; e < DMODEL; e += 64)
    acc += h1[(size_t)b * DMODEL + e] * W2[(size_t)c * DMODEL + e];
  for (int m = 32; m; m >>= 1) acc += __shfl_xor(acc, m);
  if (l == 0) out[b * 3 + c] = acc + b2[c];
}

__global__ void k_sentinel(float* out) {
  if (threadIdx.x < 6) out[threadIdx.x] = -12345.0f;
}

// ---------------- launch ----------------
typedef void (*gemm_t)(const unsigned short*, const void*, float*, unsigned short*,
                       const float*, const unsigned short*, int, int);

extern "C" void kernel_launch(void* const* d_in, const int* in_sizes, int n_in,
                              void* d_out, int out_size, void* d_ws, size_t ws_size,
                              hipStream_t stream) {
  const int*   ids = (const int*)d_in[0];
  const int*   am  = (const int*)d_in[1];
  const float* emb = (const float*)d_in[2];
  const float* Wq  = (const float*)d_in[3];
  const float* Wk  = (const float*)d_in[4];
  const float* Wv  = (const float*)d_in[5];
  const float* Wo  = (const float*)d_in[6];
  const float* Aq  = (const float*)d_in[7];
  const float* Bq  = (const float*)d_in[8];
  const float* Av  = (const float*)d_in[9];
  const float* Bv  = (const float*)d_in[10];
  const float* Wg  = (const float*)d_in[11];
  const float* Wu  = (const float*)d_in[12];
  const float* Wd  = (const float*)d_in[13];
  const float* n1  = (const float*)d_in[14];
  const float* n2  = (const float*)d_in[15];
  const float* fn  = (const float*)d_in[16];
  const float* hW1 = (const float*)d_in[17];
  const float* hb1 = (const float*)d_in[18];
  const float* hW2 = (const float*)d_in[19];
  const float* hb2 = (const float*)d_in[20];
  float* out = (float*)d_out;

  const size_t XOFF = 0;
  const size_t HOFF = 16777216;
  const size_t ROFF = 25165824;
  const size_t RSZ  = 67108864;
  const size_t TOFF = ROFF + RSZ;
  const size_t NEED = TOFF + 131072 + 262144 + 262144 + 16384 + 16384;
  if (ws_size < NEED) {
    k_sentinel<<<1, 64, 0, stream>>>(out);
    return;
  }
  const size_t W16OFF   = (NEED + 255) & ~(size_t)255;
  const size_t W16BYTES = 536870912ull;
  const bool   use16    = ws_size >= W16OFF + W16BYTES;

  char* ws = (char*)d_ws;
  float*          x   = (float*)(ws + XOFF);
  unsigned short* h   = (unsigned short*)(ws + HOFF);
  float*          q   = (float*)(ws + ROFF);
  float*          k   = (float*)(ws + ROFF + 16777216);
  float*          v   = (float*)(ws + ROFF + 33554432);
  unsigned short* o   = (unsigned short*)(ws + ROFF + 50331648);
  unsigned short* g   = (unsigned short*)(ws + ROFF);
  unsigned short* act = (unsigned short*)(ws + ROFF + 33554432);
  float* tb     = (float*)(ws + TOFF);
  float* ct     = (float*)(ws + TOFF + 131072);
  float* st     = (float*)(ws + TOFF + 131072 + 262144);
  float* pooled = (float*)(ws + TOFF + 131072 + 524288);
  float* h1     = (float*)(ws + TOFF + 131072 + 524288 + 16384);

  unsigned short* w16 = (unsigned short*)(ws + W16OFF);
  const size_t QS = 4ull * DMODEL * DMODEL;
  const size_t FS = 4ull * FFDIM * DMODEL;
  unsigned short *wq16 = w16,            *wk16 = w16 + QS,     *wv16 = w16 + 2*QS,
                 *wo16 = w16 + 3*QS,     *wg16 = w16 + 4*QS,   *wu16 = w16 + 4*QS + FS,
                 *wd16 = w16 + 4*QS + 2*FS;
  if (use16) {
    k_cvt16<<<2048, 256, 0, stream>>>(Wq, wq16, (int)(QS / 8));
    k_cvt16<<<2048, 256, 0, stream>>>(Wk, wk16, (int)(QS / 8));
    k_cvt16<<<2048, 256, 0, stream>>>(Wv, wv16, (int)(QS / 8));
    k_cvt16<<<2048, 256, 0, stream>>>(Wo, wo16, (int)(QS / 8));
    k_cvt16<<<2048, 256, 0, stream>>>(Wg, wg16, (int)(FS / 8));
    k_cvt16<<<2048, 256, 0, stream>>>(Wu, wu16, (int)(FS / 8));
    k_cvt16<<<2048, 256, 0, stream>>>(Wd, wd16, (int)(FS / 8));
  }
  gemm_t G0 = use16 ? (gemm_t)k_gemm2<0> : (gemm_t)k_gemm<0>;
  gemm_t G1 = use16 ? (gemm_t)k_gemm2<1> : (gemm_t)k_gemm<1>;
  gemm_t G2 = use16 ? (gemm_t)k_gemm2<2> : (gemm_t)k_gemm<2>;
  gemm_t G3 = use16 ? (gemm_t)k_gemm2<3> : (gemm_t)k_gemm<3>;

  k_embed<<<NTOK, 256, 0, stream>>>(ids, emb, x);
  k_rope_table<<<SEQLEN * 64 / 256, 256, 0, stream>>>(ct, st);

  dim3 g16(16, 16), g64(64, 16), ga(SEQLEN / 64, NHEAD, NBATCH);
  const size_t DD = (size_t)DMODEL * DMODEL, FD = (size_t)FFDIM * DMODEL;
  for (int lay = 0; lay < NLAYER; lay++) {
    const void* wqB = use16 ? (const void*)(wq16 + lay*DD) : (const void*)(Wq + lay*DD);
    const void* wkB = use16 ? (const void*)(wk16 + lay*DD) : (const void*)(Wk + lay*DD);
    const void* wvB = use16 ? (const void*)(wv16 + lay*DD) : (const void*)(Wv + lay*DD);
    const void* woB = use16 ? (const void*)(wo16 + lay*DD) : (const void*)(Wo + lay*DD);
    const void* wgB = use16 ? (const void*)(wg16 + lay*FD) : (const void*)(Wg + lay*FD);
    const void* wuB = use16 ? (const void*)(wu16 + lay*FD) : (const void*)(Wu + lay*FD);
    const void* wdB = use16 ? (const void*)(wd16 + lay*FD) : (const void*)(Wd + lay*FD);

    k_rmsnorm<<<NTOK, 256, 0, stream>>>(x, n1 + (size_t)lay * DMODEL, h);
    G0<<<g16, 256, 0, stream>>>(h, wqB, q, nullptr, nullptr, nullptr, DMODEL, DMODEL);
    G0<<<g16, 256, 0, stream>>>(h, wkB, k, nullptr, nullptr, nullptr, DMODEL, DMODEL);
    G0<<<g16, 256, 0, stream>>>(h, wvB, v, nullptr, nullptr, nullptr, DMODEL, DMODEL);
    k_lora_down<<<NTOK / 16, 256, 0, stream>>>(h, Aq + (size_t)lay * RLORA * DMODEL, tb);
    k_lora_up<<<NTOK * DMODEL / 256, 256, 0, stream>>>(tb, Bq + (size_t)lay * DMODEL * RLORA, q);
    k_lora_down<<<NTOK / 16, 256, 0, stream>>>(h, Av + (size_t)lay * RLORA * DMODEL, tb);
    k_lora_up<<<NTOK * DMODEL / 256, 256, 0, stream>>>(tb, Bv + (size_t)lay * DMODEL * RLORA, v);
    k_rope<<<NBATCH * SEQLEN * NHEAD * 64 / 256, 256, 0, stream>>>(q, k, ct, st);
    k_attn_mfma<<<ga, 256, 0, stream>>>(q, k, v, am, o);
    G1<<<g16, 256, 0, stream>>>(o, woB, x, nullptr, x, nullptr, DMODEL, DMODEL);
    k_rmsnorm<<<NTOK, 256, 0, stream>>>(x, n2 + (size_t)lay * DMODEL, h);
    G2<<<g64, 256, 0, stream>>>(h, wgB, nullptr, g, nullptr, nullptr, FFDIM, DMODEL);
    G3<<<g64, 256, 0, stream>>>(h, wuB, nullptr, act, nullptr, g, FFDIM, DMODEL);
    G1<<<g16, 256, 0, stream>>>(act, wdB, x, nullptr, x, nullptr, DMODEL, FFDIM);
  }
  k_pool<<<NBATCH, 256, 0, stream>>>(x, am, fn, pooled);
  k_head1<<<16, 256, 0, stream>>>(pooled, hW1, hb1, h1);
  k_head2<<<6, 64, 0, stream>>>(h1, hW2, hb2, out);
}

// Round 4
// 3297.100 us; speedup vs baseline: 2.2654x; 1.1576x over previous
//
#include <hip/hip_runtime.h>

// ---------------- model constants ----------------
#define NLAYER 4
#define DMODEL 2048
#define NHEAD  16
#define HEADD  128
#define FFDIM  8192
#define RLORA  16
#define SEQLEN 1024
#define NBATCH 2
#define NTOK   (NBATCH*SEQLEN)   // 2048
#define QKVS   6144              // fused qkv row stride

typedef __bf16 bf16x8 __attribute__((ext_vector_type(8)));
typedef float  f32x4  __attribute__((ext_vector_type(4)));
typedef unsigned short us8 __attribute__((ext_vector_type(8)));

__device__ __forceinline__ unsigned short f2b(float f) {
  unsigned int u = __builtin_bit_cast(unsigned int, f);
  u += 0x7FFFu + ((u >> 16) & 1u);          // round-to-nearest-even
  return (unsigned short)(u >> 16);
}
__device__ __forceinline__ float b2f(unsigned short s) {
  unsigned int u = ((unsigned int)s) << 16;
  return __builtin_bit_cast(float, u);
}
// V-LDS swizzle for attention (reads 2-way free, writes 2-way)
__device__ __forceinline__ int vswz(int d) {
  return (((d >> 2) & 7) ^ ((d & 3) << 1)) << 4;
}
typedef __attribute__((address_space(1))) const void* gas_t;
typedef __attribute__((address_space(3))) void* las_t;
__device__ __forceinline__ void gload16(const void* g, void* l) {
  __builtin_amdgcn_global_load_lds((gas_t)g, (las_t)l, 16, 0, 0);
}

// ---------------- embedding gather ----------------
__global__ void k_embed(const int* __restrict__ ids, const float* __restrict__ emb,
                        float* __restrict__ x) {
  int row = blockIdx.x;
  int id = ids[row];
  const float4* src = (const float4*)(emb + (size_t)id * DMODEL);
  float4* dst = (float4*)(x + (size_t)row * DMODEL);
  for (int i = threadIdx.x; i < DMODEL / 4; i += 256) dst[i] = src[i];
}

// ---------------- weight fp32 -> bf16 ----------------
__global__ void k_cvt16(const float* __restrict__ s, unsigned short* __restrict__ d, int n8) {
  int stride = gridDim.x * 256;
  for (int i = blockIdx.x * 256 + threadIdx.x; i < n8; i += stride) {
    size_t si = (size_t)i * 2;
    float4 a = ((const float4*)s)[si];
    float4 b = ((const float4*)s)[si + 1];
    us8 o;
    o[0]=f2b(a.x); o[1]=f2b(a.y); o[2]=f2b(a.z); o[3]=f2b(a.w);
    o[4]=f2b(b.x); o[5]=f2b(b.y); o[6]=f2b(b.z); o[7]=f2b(b.w);
    ((us8*)d)[i] = o;
  }
}

// ---------------- RMSNorm -> bf16 ----------------
__global__ void k_rmsnorm(const float* __restrict__ x, const float* __restrict__ w,
                          unsigned short* __restrict__ h) {
  int row = blockIdx.x, t = threadIdx.x;
  const float* xr = x + (size_t)row * DMODEL;
  float4 a = ((const float4*)xr)[t];
  float4 b = ((const float4*)xr)[t + 256];
  float ss = a.x*a.x + a.y*a.y + a.z*a.z + a.w*a.w
           + b.x*b.x + b.y*b.y + b.z*b.z + b.w*b.w;
  for (int m = 32; m; m >>= 1) ss += __shfl_xor(ss, m);
  __shared__ float red[4];
  if ((t & 63) == 0) red[t >> 6] = ss;
  __syncthreads();
  ss = red[0] + red[1] + red[2] + red[3];
  float rs = rsqrtf(ss * (1.0f / DMODEL) + 1e-5f);
  float4 wa = ((const float4*)w)[t];
  float4 wb = ((const float4*)w)[t + 256];
  ushort4 oa, ob;
  oa.x = f2b(a.x * wa.x * rs); oa.y = f2b(a.y * wa.y * rs);
  oa.z = f2b(a.z * wa.z * rs); oa.w = f2b(a.w * wa.w * rs);
  ob.x = f2b(b.x * wb.x * rs); ob.y = f2b(b.y * wb.y * rs);
  ob.z = f2b(b.z * wb.z * rs); ob.w = f2b(b.w * wb.w * rs);
  ushort4* hr = (ushort4*)(h + (size_t)row * DMODEL);
  hr[t] = oa;
  hr[t + 256] = ob;
}

// ---------------- NT GEMM fast path (bf16 A,B), BK=64, gload_lds ----------------
// LDS[row][slot s of 16B] = global chunk s ^ f3(row), f3(row)=((row>>1)&7).
// MODE 0: Cf=acc; 1: Cf=acc+Res; 2: Cb=bf16(acc); 3: Cb=bf16(silu(Gaux)*acc)
template<int MODE>
__global__ __launch_bounds__(256, 2)
void k_gemm2(const unsigned short* __restrict__ A, const void* __restrict__ Bv,
             float* __restrict__ Cf, unsigned short* __restrict__ Cb,
             const float* __restrict__ Res, const unsigned short* __restrict__ Gaux,
             int N, int K, int ldc) {
  __shared__ unsigned short As[8192];   // 128 rows x 64 elems (16KB)
  __shared__ unsigned short Bs[8192];
  const unsigned short* B = (const unsigned short*)Bv;
  const int t = threadIdx.x, l = t & 63, w = t >> 6;
  const int wr = w >> 1, wc = w & 1;
  // XCD-aware block swizzle (all grids have nwg % 8 == 0)
  const int nbx = gridDim.x;
  const int nwg = nbx * gridDim.y;
  const int bid = blockIdx.y * nbx + blockIdx.x;
  const int sid = (bid & 7) * (nwg >> 3) + (bid >> 3);
  const int m0 = (sid / nbx) << 7, n0 = (sid % nbx) << 7;
  // staging: lane -> (row, 16B slot); source chunk = slot ^ f3(row)
  const int srow0 = (w << 3) + (l >> 3);                 // rows 0..31, +32j
  const int g3 = (l & 7) ^ (4 * (w & 1) + (l >> 4));     // = slot ^ f3(srow)
  const unsigned short* Ag = A + (size_t)(m0 + srow0) * K + 8 * g3;
  const unsigned short* Bg = B + (size_t)(n0 + srow0) * K + 8 * g3;
  const size_t r32K = (size_t)32 * K;
  unsigned short* AsW = As + (w << 9);                   // w*1024 bytes
  unsigned short* BsW = Bs + (w << 9);
  // fragment read: slot = (4h+lh) ^ f3(row), lane-constant
  const int cl = l & 15, lh = l >> 4;
  const int rowA = wr * 64 + cl;
  const int rowB = wc * 64 + cl;
  const int fA = (rowA >> 1) & 7;
  const int fB = (rowB >> 1) & 7;
  const int sA0 = ((lh)     ^ fA) << 4, sA1 = ((4 + lh) ^ fA) << 4;
  const int sB0 = ((lh)     ^ fB) << 4, sB1 = ((4 + lh) ^ fB) << 4;
  f32x4 acc[4][4];
  #pragma unroll
  for (int mi = 0; mi < 4; mi++)
    #pragma unroll
    for (int ni = 0; ni < 4; ni++) { f32x4 z = {0.f, 0.f, 0.f, 0.f}; acc[mi][ni] = z; }

  for (int kt = 0; kt < K; kt += 64) {
    gload16(Ag + kt,            AsW);
    gload16(Ag + kt +   r32K,   AsW + 2048);
    gload16(Ag + kt + 2*r32K,   AsW + 4096);
    gload16(Ag + kt + 3*r32K,   AsW + 6144);
    gload16(Bg + kt,            BsW);
    gload16(Bg + kt +   r32K,   BsW + 2048);
    gload16(Bg + kt + 2*r32K,   BsW + 4096);
    gload16(Bg + kt + 3*r32K,   BsW + 6144);
    __syncthreads();                       // drains vmcnt(0) before barrier
    bf16x8 a0[4], b0[4];
    #pragma unroll
    for (int i = 0; i < 4; i++) {
      a0[i] = *(const bf16x8*)((const char*)As + (rowA + 16*i) * 128 + sA0);
      b0[i] = *(const bf16x8*)((const char*)Bs + (rowB + 16*i) * 128 + sB0);
    }
    #pragma unroll
    for (int mi = 0; mi < 4; mi++)
      #pragma unroll
      for (int ni = 0; ni < 4; ni++)
        acc[mi][ni] = __builtin_amdgcn_mfma_f32_16x16x32_bf16(a0[mi], b0[ni], acc[mi][ni], 0, 0, 0);
    bf16x8 a1[4], b1[4];
    #pragma unroll
    for (int i = 0; i < 4; i++) {
      a1[i] = *(const bf16x8*)((const char*)As + (rowA + 16*i) * 128 + sA1);
      b1[i] = *(const bf16x8*)((const char*)Bs + (rowB + 16*i) * 128 + sB1);
    }
    #pragma unroll
    for (int mi = 0; mi < 4; mi++)
      #pragma unroll
      for (int ni = 0; ni < 4; ni++)
        acc[mi][ni] = __builtin_amdgcn_mfma_f32_16x16x32_bf16(a1[mi], b1[ni], acc[mi][ni], 0, 0, 0);
    __syncthreads();
  }
  const int rbase = (l >> 4) << 2;
  #pragma unroll
  for (int mi = 0; mi < 4; mi++) {
    #pragma unroll
    for (int ni = 0; ni < 4; ni++) {
      #pragma unroll
      for (int rr = 0; rr < 4; rr++) {
        int row = m0 + wr * 64 + mi * 16 + rbase + rr;
        int col = n0 + wc * 64 + ni * 16 + cl;
        size_t idx = (size_t)row * ldc + col;
        float val = acc[mi][ni][rr];
        if constexpr (MODE == 0) Cf[idx] = val;
        if constexpr (MODE == 1) Cf[idx] = val + Res[idx];
        if constexpr (MODE == 2) Cb[idx] = f2b(val);
        if constexpr (MODE == 3) {
          float gv = b2f(Gaux[idx]);
          val *= gv / (1.0f + __expf(-gv));
          Cb[idx] = f2b(val);
        }
      }
    }
  }
}

// ---------------- NT GEMM fallback (B fp32, reg-staged, BK=32) ----------------
template<int MODE>
__global__ __launch_bounds__(256, 2)
void k_gemm(const unsigned short* __restrict__ A, const void* __restrict__ Bv,
            float* __restrict__ Cf, unsigned short* __restrict__ Cb,
            const float* __restrict__ Res, const unsigned short* __restrict__ Gaux,
            int N, int K, int ldc) {
  __shared__ unsigned char lds[128 * 32 * 2 * 2];
  unsigned char* As = lds;
  unsigned char* Bs = lds + 128 * 32 * 2;
  const int t = threadIdx.x;
  const int l = t & 63, w = t >> 6;
  const int wr = w >> 1, wc = w & 1;
  const int m0 = blockIdx.y << 7, n0 = blockIdx.x << 7;
  const int sr = t >> 1, skh = (t & 1) << 4;
  const int sByte = sr * 64 + (skh << 1);
  const int sSwz = (sr & 3) << 4;
  const unsigned short* Ap = A + (size_t)(m0 + sr) * K + skh;
  const float* Bp32 = (const float*)Bv + (size_t)(n0 + sr) * K + skh;
  const int kOff = (((l >> 4) << 4)) ^ ((l & 3) << 4);
  const int arow = wr * 64 + (l & 15);
  const int brow = wc * 64 + (l & 15);
  f32x4 acc[4][4];
  #pragma unroll
  for (int mi = 0; mi < 4; mi++)
    #pragma unroll
    for (int ni = 0; ni < 4; ni++) { f32x4 z = {0.f, 0.f, 0.f, 0.f}; acc[mi][ni] = z; }

  for (int kt = 0; kt < K; kt += 32) {
    uint4 a0 = *(const uint4*)(Ap + kt);
    uint4 a1 = *(const uint4*)(Ap + kt + 8);
    *(uint4*)(As + ((sByte)      ^ sSwz)) = a0;
    *(uint4*)(As + ((sByte + 16) ^ sSwz)) = a1;
    float4 f0 = *(const float4*)(Bp32 + kt);
    float4 f1 = *(const float4*)(Bp32 + kt + 4);
    float4 f2 = *(const float4*)(Bp32 + kt + 8);
    float4 f3 = *(const float4*)(Bp32 + kt + 12);
    us8 q0, q1;
    q0[0]=f2b(f0.x); q0[1]=f2b(f0.y); q0[2]=f2b(f0.z); q0[3]=f2b(f0.w);
    q0[4]=f2b(f1.x); q0[5]=f2b(f1.y); q0[6]=f2b(f1.z); q0[7]=f2b(f1.w);
    q1[0]=f2b(f2.x); q1[1]=f2b(f2.y); q1[2]=f2b(f2.z); q1[3]=f2b(f2.w);
    q1[4]=f2b(f3.x); q1[5]=f2b(f3.y); q1[6]=f2b(f3.z); q1[7]=f2b(f3.w);
    *(us8*)(Bs + ((sByte)      ^ sSwz)) = q0;
    *(us8*)(Bs + ((sByte + 16) ^ sSwz)) = q1;
    __syncthreads();
    bf16x8 af[4], bfr[4];
    #pragma unroll
    for (int i = 0; i < 4; i++) {
      af[i]  = *(const bf16x8*)(As + (arow + 16 * i) * 64 + kOff);
      bfr[i] = *(const bf16x8*)(Bs + (brow + 16 * i) * 64 + kOff);
    }
    #pragma unroll
    for (int mi = 0; mi < 4; mi++)
      #pragma unroll
      for (int ni = 0; ni < 4; ni++)
        acc[mi][ni] = __builtin_amdgcn_mfma_f32_16x16x32_bf16(af[mi], bfr[ni], acc[mi][ni], 0, 0, 0);
    __syncthreads();
  }
  const int rbase = (l >> 4) << 2;
  const int cl = l & 15;
  #pragma unroll
  for (int mi = 0; mi < 4; mi++) {
    #pragma unroll
    for (int ni = 0; ni < 4; ni++) {
      #pragma unroll
      for (int rr = 0; rr < 4; rr++) {
        int row = m0 + wr * 64 + mi * 16 + rbase + rr;
        int col = n0 + wc * 64 + ni * 16 + cl;
        size_t idx = (size_t)row * ldc + col;
        float val = acc[mi][ni][rr];
        if constexpr (MODE == 0) Cf[idx] = val;
        if constexpr (MODE == 1) Cf[idx] = val + Res[idx];
        if constexpr (MODE == 2) Cb[idx] = f2b(val);
        if constexpr (MODE == 3) {
          float gv = b2f(Gaux[idx]);
          val *= gv / (1.0f + __expf(-gv));
          Cb[idx] = f2b(val);
        }
      }
    }
  }
}

// ---------------- LoRA ----------------
__global__ void k_lora_down(const unsigned short* __restrict__ h, const float* __restrict__ Am,
                            float* __restrict__ tb) {
  int t = threadIdx.x;
  int m = blockIdx.x * 16 + (t >> 4), r = t & 15;
  const unsigned short* hr = h + (size_t)m * DMODEL;
  const float* ar = Am + (size_t)r * DMODEL;
  float acc = 0.f;
  for (int d = 0; d < DMODEL; d += 4) {
    ushort4 hv = *(const ushort4*)(hr + d);
    float4 av = *(const float4*)(ar + d);
    acc += b2f(hv.x)*av.x + b2f(hv.y)*av.y + b2f(hv.z)*av.z + b2f(hv.w)*av.w;
  }
  tb[(size_t)m * RLORA + r] = acc;
}

__global__ void k_lora_up(const float* __restrict__ tb, const float* __restrict__ Bm,
                          float* __restrict__ out, int ldc) {
  int tid = blockIdx.x * 256 + threadIdx.x;
  int m = tid >> 11, e = tid & (DMODEL - 1);
  const float* tr = tb + (size_t)m * RLORA;
  const float* br = Bm + (size_t)e * RLORA;
  float acc = 0.f;
  #pragma unroll
  for (int r = 0; r < RLORA; r += 4) {
    float4 tv = *(const float4*)(tr + r);
    float4 bv = *(const float4*)(br + r);
    acc += tv.x*bv.x + tv.y*bv.y + tv.z*bv.z + tv.w*bv.w;
  }
  out[(size_t)m * ldc + e] += 2.0f * acc;      // ALPHA_OVER_R = 32/16
}

// ---------------- RoPE tables ----------------
__global__ void k_rope_table(float* __restrict__ ct, float* __restrict__ st) {
  int tid = blockIdx.x * 256 + threadIdx.x;
  int s = tid >> 6, i = tid & 63;
  float inv = __expf(-((float)i / 64.0f) * logf(10000.0f));
  float ang = (float)s * inv;
  ct[tid] = cosf(ang);
  st[tid] = sinf(ang);
}

// RoPE from fused qkv (f32, stride QKVS) -> dense bf16 qb/kb/vb
__global__ void k_rope2(const float* __restrict__ qkv,
                        const float* __restrict__ ct, const float* __restrict__ st,
                        unsigned short* __restrict__ qb, unsigned short* __restrict__ kb,
                        unsigned short* __restrict__ vb) {
  int tid = blockIdx.x * 256 + threadIdx.x;    // B*S*H*64
  int i = tid & 63;
  int hh = (tid >> 6) & (NHEAD - 1);
  int s = (tid >> 10) & (SEQLEN - 1);
  int b = tid >> 20;
  size_t ibase = ((size_t)(b * SEQLEN + s)) * QKVS + hh * HEADD;
  size_t obase = ((size_t)(b * SEQLEN + s)) * DMODEL + hh * HEADD;
  float c = ct[s * 64 + i], sn = st[s * 64 + i];
  float q0 = qkv[ibase + i], q1 = qkv[ibase + i + 64];
  qb[obase + i]      = f2b(q0 * c - q1 * sn);
  qb[obase + i + 64] = f2b(q1 * c + q0 * sn);
  float k0 = qkv[ibase + 2048 + i], k1 = qkv[ibase + 2048 + i + 64];
  kb[obase + i]      = f2b(k0 * c - k1 * sn);
  kb[obase + i + 64] = f2b(k1 * c + k0 * sn);
  vb[obase + i]      = f2b(qkv[ibase + 4096 + i]);
  vb[obase + i + 64] = f2b(qkv[ibase + 4096 + i + 64]);
}

// ---------------- fused causal attention, MFMA bf16 inputs ----------------
__global__ __launch_bounds__(256, 2)
void k_attn_bf16(const unsigned short* __restrict__ qbp, const unsigned short* __restrict__ kbp,
                 const unsigned short* __restrict__ vbp, const int* __restrict__ am,
                 unsigned short* __restrict__ o) {
  __shared__ unsigned char Kls[64 * 256];   // [n][128d] bf16, swz (n&7)<<4
  __shared__ unsigned char Vls[128 * 128];  // [d][64n] bf16 transposed, swz vswz(d)
  __shared__ unsigned char Pls[64 * 128];   // [q][64n] bf16, swz (q&7)<<4
  const int qt = blockIdx.x, hh = blockIdx.y, b = blockIdx.z;
  const int t = threadIdx.x, l = t & 63, w = t >> 6;
  const int cl = l & 15, lh = l >> 4;
  const int rbase = lh << 2;

  // stage Q (bf16 copy)
  for (int ii = 0; ii < 4; ii++) {
    int idx = t + 256 * ii; int row = idx >> 4; int c = idx & 15;
    uint4 u = *(const uint4*)(qbp + ((size_t)(b*SEQLEN + qt*64 + row)) * DMODEL + hh * HEADD + c * 8);
    *(uint4*)(Kls + ((row * 256 + c * 16) ^ ((row & 7) << 4))) = u;
  }
  __syncthreads();
  bf16x8 qf[4];
  {
    int row = w * 16 + cl;
    int swz = (row & 7) << 4;
    #pragma unroll
    for (int kt = 0; kt < 4; kt++)
      qf[kt] = *(const bf16x8*)(Kls + ((row * 256 + kt * 64 + lh * 16) ^ swz));
  }

  f32x4 oacc[8];
  #pragma unroll
  for (int i = 0; i < 8; i++) { f32x4 z = {0.f,0.f,0.f,0.f}; oacc[i] = z; }
  float mrun[4], lrun[4];
  #pragma unroll
  for (int r = 0; r < 4; r++) { mrun[r] = -3e38f; lrun[r] = 0.f; }

  for (int kb = 0; kb <= qt; kb++) {
    __syncthreads();
    // stage K tile [64 rows][128 d]
    for (int ii = 0; ii < 4; ii++) {
      int idx = t + 256 * ii; int row = idx >> 4; int c = idx & 15;
      uint4 u = *(const uint4*)(kbp + ((size_t)(b*SEQLEN + kb*64 + row)) * DMODEL + hh * HEADD + c * 8);
      *(uint4*)(Kls + ((row * 256 + c * 16) ^ ((row & 7) << 4))) = u;
    }
    // stage V transposed [128 d][64 n] via lane-pair word packing
    for (int ii = 0; ii < 4; ii++) {
      int idx = t + 256 * ii;
      int n = idx >> 4, dc = idx & 15;
      uint4 a = *(const uint4*)(vbp + ((size_t)(b*SEQLEN + kb*64 + n)) * DMODEL + hh * HEADD + dc * 8);
      uint4 p;
      p.x = __shfl_xor(a.x, 16); p.y = __shfl_xor(a.y, 16);
      p.z = __shfl_xor(a.z, 16); p.w = __shfl_xor(a.w, 16);
      if (!(l & 16)) {                       // n even lanes write pairs (n, n+1)
        int d0 = dc * 8, nb = n * 2;
        unsigned int wd[8];
        wd[0] = (a.x & 0xffffu) | (p.x << 16);
        wd[1] = (a.x >> 16)     | (p.x & 0xffff0000u);
        wd[2] = (a.y & 0xffffu) | (p.y << 16);
        wd[3] = (a.y >> 16)     | (p.y & 0xffff0000u);
        wd[4] = (a.z & 0xffffu) | (p.z << 16);
        wd[5] = (a.z >> 16)     | (p.z & 0xffff0000u);
        wd[6] = (a.w & 0xffffu) | (p.w << 16);
        wd[7] = (a.w >> 16)     | (p.w & 0xffff0000u);
        #pragma unroll
        for (int e = 0; e < 8; e++)
          *(unsigned int*)(Vls + (((d0 + e) * 128 + nb) ^ vswz(d0 + e))) = wd[e];
      }
    }
    __syncthreads();
    // S = Q K^T
    f32x4 sacc[4];
    #pragma unroll
    for (int nt = 0; nt < 4; nt++) { f32x4 z = {0.f,0.f,0.f,0.f}; sacc[nt] = z; }
    #pragma unroll
    for (int kt = 0; kt < 4; kt++) {
      #pragma unroll
      for (int nt = 0; nt < 4; nt++) {
        int row = nt * 16 + cl;
        bf16x8 kf = *(const bf16x8*)(Kls + ((row * 256 + kt * 64 + lh * 16) ^ ((row & 7) << 4)));
        sacc[nt] = __builtin_amdgcn_mfma_f32_16x16x32_bf16(qf[kt], kf, sacc[nt], 0, 0, 0);
      }
    }
    // online softmax
    float p[4][4];
    float mt[4] = {-3e38f, -3e38f, -3e38f, -3e38f};
    #pragma unroll
    for (int nt = 0; nt < 4; nt++) {
      int kg = kb * 64 + nt * 16 + cl;
      float pad = (1.0f - (float)am[b * SEQLEN + kg]) * (-1e9f);
      #pragma unroll
      for (int r = 0; r < 4; r++) {
        int qg = qt * 64 + w * 16 + rbase + r;
        float s = sacc[nt][r] * 0.08838834764831845f + pad;
        if (kg > qg) s = -1e30f;
        p[nt][r] = s;
        mt[r] = fmaxf(mt[r], s);
      }
    }
    #pragma unroll
    for (int r = 0; r < 4; r++) {
      float m = mt[r];
      m = fmaxf(m, __shfl_xor(m, 1)); m = fmaxf(m, __shfl_xor(m, 2));
      m = fmaxf(m, __shfl_xor(m, 4)); m = fmaxf(m, __shfl_xor(m, 8));
      mt[r] = m;
    }
    float corr[4];
    #pragma unroll
    for (int r = 0; r < 4; r++) {
      float mnew = fmaxf(mrun[r], mt[r]);
      corr[r] = __expf(mrun[r] - mnew);
      mrun[r] = mnew;
    }
    float ps[4] = {0.f, 0.f, 0.f, 0.f};
    #pragma unroll
    for (int nt = 0; nt < 4; nt++)
      #pragma unroll
      for (int r = 0; r < 4; r++) {
        p[nt][r] = __expf(p[nt][r] - mrun[r]);
        ps[r] += p[nt][r];
      }
    #pragma unroll
    for (int r = 0; r < 4; r++) {
      float s = ps[r];
      s += __shfl_xor(s, 1); s += __shfl_xor(s, 2);
      s += __shfl_xor(s, 4); s += __shfl_xor(s, 8);
      lrun[r] = lrun[r] * corr[r] + s;
    }
    #pragma unroll
    for (int nt = 0; nt < 4; nt++)
      #pragma unroll
      for (int r = 0; r < 4; r++) {
        int row = w * 16 + rbase + r;
        *(unsigned short*)(Pls + ((row * 128 + (nt * 16 + cl) * 2) ^ ((row & 7) << 4))) = f2b(p[nt][r]);
      }
    #pragma unroll
    for (int dt = 0; dt < 8; dt++)
      #pragma unroll
      for (int r = 0; r < 4; r++) oacc[dt][r] *= corr[r];
    {
      int prow = w * 16 + cl, pswz = (prow & 7) << 4;
      bf16x8 pf0 = *(const bf16x8*)(Pls + ((prow * 128 +  0 + lh * 16) ^ pswz));
      bf16x8 pf1 = *(const bf16x8*)(Pls + ((prow * 128 + 64 + lh * 16) ^ pswz));
      #pragma unroll
      for (int dt = 0; dt < 8; dt++) {
        int drow = dt * 16 + cl;
        bf16x8 vf0 = *(const bf16x8*)(Vls + ((drow * 128 +  0 + lh * 16) ^ vswz(drow)));
        bf16x8 vf1 = *(const bf16x8*)(Vls + ((drow * 128 + 64 + lh * 16) ^ vswz(drow)));
        oacc[dt] = __builtin_amdgcn_mfma_f32_16x16x32_bf16(pf0, vf0, oacc[dt], 0, 0, 0);
        oacc[dt] = __builtin_amdgcn_mfma_f32_16x16x32_bf16(pf1, vf1, oacc[dt], 0, 0, 0);
      }
    }
  }
  size_t obase = (((size_t)b * SEQLEN + qt * 64 + w * 16) * NHEAD + hh) * HEADD;
  #pragma unroll
  for (int r = 0; r < 4; r++) {
    float inv = 1.0f / lrun[r];
    int row = rbase + r;
    #pragma unroll
    for (int dt = 0; dt < 8; dt++)
      o[obase + (size_t)row * (NHEAD * HEADD) + dt * 16 + cl] = f2b(oacc[dt][r] * inv);
  }
}

// ---------------- pooling + final RMS ----------------
__global__ void k_pool(const float* __restrict__ x, const int* __restrict__ am,
                       const float* __restrict__ fn, float* __restrict__ pooled) {
  int b = blockIdx.x, t = threadIdx.x;
  __shared__ float red[4];
  float fc = 0.f;
  for (int i = t; i < SEQLEN; i += 256) fc += (float)am[b * SEQLEN + i];
  for (int m = 32; m; m >>= 1) fc += __shfl_xor(fc, m);
  if ((t & 63) == 0) red[t >> 6] = fc;
  __syncthreads();
  int idx = (int)(red[0] + red[1] + red[2] + red[3]) - 1;
  const float* xr = x + ((size_t)b * SEQLEN + idx) * DMODEL;
  float4 a = ((const float4*)xr)[t], c = ((const float4*)xr)[t + 256];
  float ss = a.x*a.x + a.y*a.y + a.z*a.z + a.w*a.w
           + c.x*c.x + c.y*c.y + c.z*c.z + c.w*c.w;
  for (int m = 32; m; m >>= 1) ss += __shfl_xor(ss, m);
  __syncthreads();
  if ((t & 63) == 0) red[t >> 6] = ss;
  __syncthreads();
  ss = red[0] + red[1] + red[2] + red[3];
  float rs = rsqrtf(ss * (1.0f / DMODEL) + 1e-5f);
  float4 w0 = ((const float4*)fn)[t], w1 = ((const float4*)fn)[t + 256];
  float4 o0, o1;
  o0.x = a.x*rs*w0.x; o0.y = a.y*rs*w0.y; o0.z = a.z*rs*w0.z; o0.w = a.w*rs*w0.w;
  o1.x = c.x*rs*w1.x; o1.y = c.y*rs*w1.y; o1.z = c.z*rs*w1.z; o1.w = c.w*rs*w1.w;
  ((float4*)(pooled + (size_t)b * DMODEL))[t] = o0;
  ((float4*)(pooled + (size_t)b * DMODEL))[t + 256] = o1;
}

// ---------------- classification head ----------------
__global__ void k_head1(const float* __restrict__ pooled, const float* __restrict__ W1,
                        const float* __restrict__ b1, float* __restrict__ h1) {
  int bi = blockIdx.x;
  int b = bi >> 3, e = ((bi & 7) << 8) + threadIdx.x;
  const float* pr = pooled + (size_t)b * DMODEL;
  const float* wr = W1 + (size_t)e * DMODEL;
  float acc = 0.f;
  for (int d = 0; d < DMODEL; d += 4) {
    float4 pv = *(const float4*)(pr + d);
    float4 wv = *(const float4*)(wr + d);
    acc += pv.x*wv.x + pv.y*wv.y + pv.z*wv.z + pv.w*wv.w;
  }
  h1[(size_t)b * DMODEL + e] = tanhf(acc + b1[e]);
}

__global__ void k_head2(const float* __restrict__ h1, const float* __restrict__ W2,
                        const float* __restrict__ b2, float* __restrict__ out) {
  int bi = blockIdx.x;
  int b = bi / 3, c = bi % 3;
  int l = threadIdx.x;
  float acc = 0.f;
  for (int e = l; e < DMODEL; e += 64)
    acc += h1[(size_t)b * DMODEL + e] * W2[(size_t)c * DMODEL + e];
  for (int m = 32; m; m >>= 1) acc += __shfl_xor(acc, m);
  if (l == 0) out[b * 3 + c] = acc + b2[c];
}

__global__ void k_sentinel(float* out) {
  if (threadIdx.x < 6) out[threadIdx.x] = -12345.0f;
}

// ---------------- launch ----------------
typedef void (*gemm_t)(const unsigned short*, const void*, float*, unsigned short*,
                       const float*, const unsigned short*, int, int, int);

extern "C" void kernel_launch(void* const* d_in, const int* in_sizes, int n_in,
                              void* d_out, int out_size, void* d_ws, size_t ws_size,
                              hipStream_t stream) {
  const int*   ids = (const int*)d_in[0];
  const int*   am  = (const int*)d_in[1];
  const float* emb = (const float*)d_in[2];
  const float* Wq  = (const float*)d_in[3];
  const float* Wk  = (const float*)d_in[4];
  const float* Wv  = (const float*)d_in[5];
  const float* Wo  = (const float*)d_in[6];
  const float* Aq  = (const float*)d_in[7];
  const float* Bq  = (const float*)d_in[8];
  const float* Av  = (const float*)d_in[9];
  const float* Bv  = (const float*)d_in[10];
  const float* Wg  = (const float*)d_in[11];
  const float* Wu  = (const float*)d_in[12];
  const float* Wd  = (const float*)d_in[13];
  const float* n1  = (const float*)d_in[14];
  const float* n2  = (const float*)d_in[15];
  const float* fn  = (const float*)d_in[16];
  const float* hW1 = (const float*)d_in[17];
  const float* hb1 = (const float*)d_in[18];
  const float* hW2 = (const float*)d_in[19];
  const float* hb2 = (const float*)d_in[20];
  float* out = (float*)d_out;

  // workspace layout
  const size_t XOFF   = 0;                        // x f32 16MB
  const size_t HOFF   = 16777216;                 // h bf16 8MB
  const size_t QKVOFF = 25165824;                 // qkv f32 48MB
  const size_t QBOFF  = 75497472;                 // qb bf16 8MB
  const size_t KBOFF  = 83886080;                 // kb bf16 8MB
  const size_t VBOFF  = 92274688;                 // vb bf16 8MB
  const size_t OOFF   = 100663296;                // o bf16 8MB
  const size_t TOFF   = 109051904;                // tails
  // g (32MB) at QKVOFF, act (32MB) at QKVOFF+32MB (overlaps qb/kb; both dead)
  const size_t NEED = TOFF + 131072 + 131072 + 262144 + 262144 + 16384 + 16384;
  if (ws_size < NEED) {
    k_sentinel<<<1, 64, 0, stream>>>(out);
    return;
  }
  const size_t W16OFF   = (NEED + 255) & ~(size_t)255;
  const size_t W16BYTES = 536870912ull;
  const bool   use16    = ws_size >= W16OFF + W16BYTES;

  char* ws = (char*)d_ws;
  float*          x   = (float*)(ws + XOFF);
  unsigned short* h   = (unsigned short*)(ws + HOFF);
  float*          qkv = (float*)(ws + QKVOFF);
  unsigned short* qb  = (unsigned short*)(ws + QBOFF);
  unsigned short* kb  = (unsigned short*)(ws + KBOFF);
  unsigned short* vb  = (unsigned short*)(ws + VBOFF);
  unsigned short* o   = (unsigned short*)(ws + OOFF);
  unsigned short* g   = (unsigned short*)(ws + QKVOFF);
  unsigned short* act = (unsigned short*)(ws + QKVOFF + 33554432);
  float* tbq    = (float*)(ws + TOFF);
  float* tbv    = (float*)(ws + TOFF + 131072);
  float* ct     = (float*)(ws + TOFF + 262144);
  float* st     = (float*)(ws + TOFF + 262144 + 262144);
  float* pooled = (float*)(ws + TOFF + 262144 + 524288);
  float* h1     = (float*)(ws + TOFF + 262144 + 524288 + 16384);

  unsigned short* w16 = (unsigned short*)(ws + W16OFF);
  const size_t DD = (size_t)DMODEL * DMODEL;      // 4M elems
  const size_t FD = (size_t)FFDIM * DMODEL;       // 16M elems
  unsigned short* wqkv16 = w16;                              // L*3*DD
  unsigned short* wo16   = w16 + 4ull * 3 * DD;              // L*DD
  unsigned short* wg16   = wo16 + 4ull * DD;                 // L*FD
  unsigned short* wu16   = wg16 + 4ull * FD;
  unsigned short* wd16   = wu16 + 4ull * FD;
  if (use16) {
    for (int lay = 0; lay < NLAYER; lay++) {
      k_cvt16<<<2048, 256, 0, stream>>>(Wq + lay*DD, wqkv16 + lay*3*DD,          (int)(DD / 8));
      k_cvt16<<<2048, 256, 0, stream>>>(Wk + lay*DD, wqkv16 + lay*3*DD + DD,     (int)(DD / 8));
      k_cvt16<<<2048, 256, 0, stream>>>(Wv + lay*DD, wqkv16 + lay*3*DD + 2*DD,   (int)(DD / 8));
    }
    k_cvt16<<<2048, 256, 0, stream>>>(Wo, wo16, (int)(4 * DD / 8));
    k_cvt16<<<2048, 256, 0, stream>>>(Wg, wg16, (int)(4 * FD / 8));
    k_cvt16<<<2048, 256, 0, stream>>>(Wu, wu16, (int)(4 * FD / 8));
    k_cvt16<<<2048, 256, 0, stream>>>(Wd, wd16, (int)(4 * FD / 8));
  }

  k_embed<<<NTOK, 256, 0, stream>>>(ids, emb, x);
  k_rope_table<<<SEQLEN * 64 / 256, 256, 0, stream>>>(ct, st);

  dim3 g16(16, 16), g48(48, 16), g64(64, 16), ga(SEQLEN / 64, NHEAD, NBATCH);
  for (int lay = 0; lay < NLAYER; lay++) {
    k_rmsnorm<<<NTOK, 256, 0, stream>>>(x, n1 + (size_t)lay * DMODEL, h);
    if (use16) {
      k_gemm2<0><<<g48, 256, 0, stream>>>(h, wqkv16 + lay*3*DD, qkv, nullptr, nullptr, nullptr, QKVS, DMODEL, QKVS);
    } else {
      k_gemm<0><<<g16, 256, 0, stream>>>(h, Wq + lay*DD, qkv,        nullptr, nullptr, nullptr, DMODEL, DMODEL, QKVS);
      k_gemm<0><<<g16, 256, 0, stream>>>(h, Wk + lay*DD, qkv + 2048, nullptr, nullptr, nullptr, DMODEL, DMODEL, QKVS);
      k_gemm<0><<<g16, 256, 0, stream>>>(h, Wv + lay*DD, qkv + 4096, nullptr, nullptr, nullptr, DMODEL, DMODEL, QKVS);
    }
    k_lora_down<<<NTOK / 16, 256, 0, stream>>>(h, Aq + (size_t)lay * RLORA * DMODEL, tbq);
    k_lora_up<<<NTOK * DMODEL / 256, 256, 0, stream>>>(tbq, Bq + (size_t)lay * DMODEL * RLORA, qkv, QKVS);
    k_lora_down<<<NTOK / 16, 256, 0, stream>>>(h, Av + (size_t)lay * RLORA * DMODEL, tbv);
    k_lora_up<<<NTOK * DMODEL / 256, 256, 0, stream>>>(tbv, Bv + (size_t)lay * DMODEL * RLORA, qkv + 4096, QKVS);
    k_rope2<<<NBATCH * SEQLEN * NHEAD * 64 / 256, 256, 0, stream>>>(qkv, ct, st, qb, kb, vb);
    k_attn_bf16<<<ga, 256, 0, stream>>>(qb, kb, vb, am, o);
    if (use16) {
      k_gemm2<1><<<g16, 256, 0, stream>>>(o, wo16 + lay*DD, x, nullptr, x, nullptr, DMODEL, DMODEL, DMODEL);
    } else {
      k_gemm<1><<<g16, 256, 0, stream>>>(o, Wo + lay*DD, x, nullptr, x, nullptr, DMODEL, DMODEL, DMODEL);
    }
    k_rmsnorm<<<NTOK, 256, 0, stream>>>(x, n2 + (size_t)lay * DMODEL, h);
    if (use16) {
      k_gemm2<2><<<g64, 256, 0, stream>>>(h, wg16 + lay*FD, nullptr, g, nullptr, nullptr, FFDIM, DMODEL, FFDIM);
      k_gemm2<3><<<g64, 256, 0, stream>>>(h, wu16 + lay*FD, nullptr, act, nullptr, g, FFDIM, DMODEL, FFDIM);
      k_gemm2<1><<<g16, 256, 0, stream>>>(act, wd16 + lay*FD, x, nullptr, x, nullptr, DMODEL, FFDIM, DMODEL);
    } else {
      k_gemm<2><<<g64, 256, 0, stream>>>(h, Wg + lay*FD, nullptr, g, nullptr, nullptr, FFDIM, DMODEL, FFDIM);
      k_gemm<3><<<g64, 256, 0, stream>>>(h, Wu + lay*FD, nullptr, act, nullptr, g, FFDIM, DMODEL, FFDIM);
      k_gemm<1><<<g16, 256, 0, stream>>>(act, Wd + lay*FD, x, nullptr, x, nullptr, DMODEL, FFDIM, DMODEL);
    }
  }
  k_pool<<<NBATCH, 256, 0, stream>>>(x, am, fn, pooled);
  k_head1<<<16, 256, 0, stream>>>(pooled, hW1, hb1, h1);
  k_head2<<<6, 64, 0, stream>>>(h1, hW2, hb2, out);
}